// Round 2
// baseline (675.492 us; speedup 1.0000x reference)
//
#include <hip/hip_runtime.h>
#include <hip/hip_bf16.h>

#define BB 2
#define NN 8192
#define SPL 4
#define CAND (NN/SPL)
#define NPTS (BB*NN)

// ---- workspace layout (units: 4-byte words), total ~18.2 MB ----
#define POS4_OFF 0u
#define WBUF_OFF 65536u
#define XB_OFF   (WBUF_OFF + 33792u)
#define PART_OFF XB_OFF                  /* PART dead after k2; XB born at k3 */
#define QB_OFF   (XB_OFF + 1048576u)
#define KB_OFF   (QB_OFF + 1048576u)
#define VB_OFF   (KB_OFF + 1048576u)
#define IDX_OFF  (VB_OFF + 1048576u)

// ---- wbuf internal offsets (words) ----
#define W_EMB 0
#define W_Q   4096
#define W_K   8192
#define W_V   12288
#define W_PE2 16384
#define W_AT1 20480
#define W_AT2 24576
#define W_OUT 28672
#define W_PE1 32768
#define B_EMB 32960
#define B_PE1 33024
#define B_PE2 33088
#define B_AT1 33152
#define B_AT2 33216
#define B_OUT 33280

// ============================ K0: stage pos->float4, weights->wbuf ============
__global__ __launch_bounds__(256) void k0_stage(
    const float* __restrict__ pos,
    const float* __restrict__ emb_w, const float* __restrict__ emb_b,
    const float* __restrict__ wq, const float* __restrict__ wk,
    const float* __restrict__ wv,
    const float* __restrict__ pe_w1, const float* __restrict__ pe_b1,
    const float* __restrict__ pe_w2, const float* __restrict__ pe_b2,
    const float* __restrict__ at_w1, const float* __restrict__ at_b1,
    const float* __restrict__ at_w2, const float* __restrict__ at_b2,
    const float* __restrict__ out_w, const float* __restrict__ out_b,
    float* __restrict__ ws)
{
  int t = blockIdx.x * 256 + threadIdx.x;
  if (t < NPTS) {
    float* o = ws + POS4_OFF + t * 4;
    o[0] = pos[t * 3 + 0];
    o[1] = pos[t * 3 + 1];
    o[2] = pos[t * 3 + 2];
    o[3] = 0.f;
    return;
  }
  t -= NPTS;
  float* wbuf = ws + WBUF_OFF;
  if (t < 32768) {
    const float* s;
    switch (t >> 12) {
      case 0: s = emb_w; break;
      case 1: s = wq;    break;
      case 2: s = wk;    break;
      case 3: s = wv;    break;
      case 4: s = pe_w2; break;
      case 5: s = at_w1; break;
      case 6: s = at_w2; break;
      default: s = out_w; break;
    }
    wbuf[t] = s[t & 4095];
    return;
  }
  t -= 32768;
  if (t < 192) { wbuf[W_PE1 + t] = pe_w1[t]; return; }
  t -= 192;
  if (t < 384) {
    const float* s;
    switch (t >> 6) {
      case 0: s = emb_b; break;
      case 1: s = pe_b1; break;
      case 2: s = pe_b2; break;
      case 3: s = at_b1; break;
      case 4: s = at_b2; break;
      default: s = out_b; break;
    }
    wbuf[B_EMB + t] = s[t & 63];
  }
}

// ============================ K1: brute-force KNN (split over candidates) =====
// packed key = (19 high bits of f32 distance) | (13-bit candidate idx)
__global__ __launch_bounds__(64) void k1_knn(const float* __restrict__ pos4,
                                             unsigned* __restrict__ part)
{
  const int b = blockIdx.x;
  const int s = blockIdx.z;
  const int n = blockIdx.y * 64 + threadIdx.x;
  const float4* __restrict__ allp = (const float4*)pos4;
  const float4 mp = allp[b * NN + n];
  const float4* __restrict__ cand = allp + (b * NN + s * CAND);
  unsigned m[16];
#pragma unroll
  for (int i = 0; i < 16; i++) m[i] = 0xFFFFFFFFu;
  const unsigned jb = (unsigned)(s * CAND);
  for (int j = 0; j < CAND; j++) {
    float4 cp = cand[j];                       // uniform address -> scalar loads
    float dx = mp.x - cp.x, dy = mp.y - cp.y, dz = mp.z - cp.z;
    float d2 = fmaf(dx, dx, fmaf(dy, dy, dz * dz));
    unsigned pk = (__float_as_uint(d2) & 0xFFFFE000u) | (jb + (unsigned)j);
    if (pk < m[15]) {
      m[15] = pk;
#pragma unroll
      for (int i = 15; i > 0; i--) {           // one bubble pass: min/max pairs
        unsigned a = m[i - 1], c = m[i];
        m[i - 1] = a < c ? a : c;
        m[i]     = a < c ? c : a;
      }
    }
  }
  unsigned base = ((unsigned)(b * NN + n) * SPL + (unsigned)s) * 16u;
  uint4* o = (uint4*)(part + base);
  o[0] = make_uint4(m[0], m[1], m[2], m[3]);
  o[1] = make_uint4(m[4], m[5], m[6], m[7]);
  o[2] = make_uint4(m[8], m[9], m[10], m[11]);
  o[3] = make_uint4(m[12], m[13], m[14], m[15]);
}

// ============================ K2: merge the 4 sorted 16-lists ==================
__global__ __launch_bounds__(256) void k2_merge(const unsigned* __restrict__ part,
                                                int* __restrict__ knn_idx)
{
  __shared__ unsigned lds[64][256];   // [entry][thread]
  const int tid = threadIdx.x;
  const int g = blockIdx.x * 256 + tid;
  const uint4* src = (const uint4*)(part + (unsigned)g * 64u);
#pragma unroll
  for (int i = 0; i < 16; i++) {
    uint4 v = src[i];
    lds[i * 4 + 0][tid] = v.x;
    lds[i * 4 + 1][tid] = v.y;
    lds[i * 4 + 2][tid] = v.z;
    lds[i * 4 + 3][tid] = v.w;
  }
  unsigned h0 = 0, h1 = 0, h2 = 0, h3 = 0;
  unsigned v0 = lds[0][tid], v1 = lds[16][tid], v2 = lds[32][tid], v3 = lds[48][tid];
  const int base = (g >> 13) * NN;   // batch offset -> global rows
  int outv[16];
#pragma unroll
  for (int stp = 0; stp < 16; stp++) {
    unsigned ma = v0 < v1 ? v0 : v1;
    unsigned mb = v2 < v3 ? v2 : v3;
    unsigned m = ma < mb ? ma : mb;
    outv[stp] = base + (int)(m & 0x1FFFu);
    if (v0 == m)      { h0++; v0 = (h0 < 16) ? lds[h0][tid]      : 0xFFFFFFFFu; }
    else if (v1 == m) { h1++; v1 = (h1 < 16) ? lds[16 + h1][tid] : 0xFFFFFFFFu; }
    else if (v2 == m) { h2++; v2 = (h2 < 16) ? lds[32 + h2][tid] : 0xFFFFFFFFu; }
    else              { h3++; v3 = (h3 < 16) ? lds[48 + h3][tid] : 0xFFFFFFFFu; }
  }
  int4* o = (int4*)(knn_idx + g * 16);
  o[0] = make_int4(outv[0], outv[1], outv[2], outv[3]);
  o[1] = make_int4(outv[4], outv[5], outv[6], outv[7]);
  o[2] = make_int4(outv[8], outv[9], outv[10], outv[11]);
  o[3] = make_int4(outv[12], outv[13], outv[14], outv[15]);
}

// ============================ K3: x = features @ emb_w + emb_b =================
__global__ __launch_bounds__(256) void k3_emb(const float* __restrict__ feat,
                                              const float* __restrict__ wb,
                                              float* __restrict__ xo)
{
  __shared__ float wl[4096];
  for (int i = threadIdx.x; i < 4096; i += 256) wl[i] = wb[W_EMB + i];
  __syncthreads();
  const int col = threadIdx.x & 63;
  const int rg = threadIdx.x >> 6;
  const int row0 = blockIdx.x * 128 + rg * 32;
  const int rowu = __builtin_amdgcn_readfirstlane(row0);
  float acc[32];
  float bias = wb[B_EMB + col];
#pragma unroll
  for (int r = 0; r < 32; r++) acc[r] = bias;
  for (int c = 0; c < 64; c++) {
    float w = wl[c * 64 + col];
    const float* fp = feat + rowu * 64 + c;   // uniform -> scalar loads
#pragma unroll
    for (int r = 0; r < 32; r++) acc[r] = fmaf(fp[r * 64], w, acc[r]);
  }
#pragma unroll
  for (int r = 0; r < 32; r++) xo[(row0 + r) * 64 + col] = acc[r];
}

// ============================ K4: q,k,v = x @ {wq,wk,wv} =======================
__global__ __launch_bounds__(256) void k4_qkv(const float* __restrict__ xb,
                                              const float* __restrict__ wb,
                                              float* __restrict__ qo,
                                              float* __restrict__ ko,
                                              float* __restrict__ vo)
{
  __shared__ float wl[12288];
  for (int i = threadIdx.x; i < 12288; i += 256) wl[i] = wb[W_Q + i];
  __syncthreads();
  const int col = threadIdx.x & 63;
  const int rg = threadIdx.x >> 6;
  const int row0 = blockIdx.x * 64 + rg * 16;
  const int rowu = __builtin_amdgcn_readfirstlane(row0);
  float aq[16], ak[16], av[16];
#pragma unroll
  for (int r = 0; r < 16; r++) { aq[r] = 0.f; ak[r] = 0.f; av[r] = 0.f; }
  for (int c = 0; c < 64; c++) {
    float w0 = wl[c * 64 + col];
    float w1 = wl[4096 + c * 64 + col];
    float w2 = wl[8192 + c * 64 + col];
    const float* fp = xb + rowu * 64 + c;     // uniform -> scalar loads
#pragma unroll
    for (int r = 0; r < 16; r++) {
      float xv = fp[r * 64];
      aq[r] = fmaf(xv, w0, aq[r]);
      ak[r] = fmaf(xv, w1, ak[r]);
      av[r] = fmaf(xv, w2, av[r]);
    }
  }
#pragma unroll
  for (int r = 0; r < 16; r++) {
    qo[(row0 + r) * 64 + col] = aq[r];
    ko[(row0 + r) * 64 + col] = ak[r];
    vo[(row0 + r) * 64 + col] = av[r];
  }
}

// ============================ K5: fused posenc + attn MLPs + softmax + out =====
#define MATVEC(WMAT, BIASV, ACC)                                              \
  {                                                                           \
    _Pragma("unroll")                                                         \
    for (int j = 0; j < 16; j++) ACC[j] = (BIASV);                            \
    for (int cs = 0; cs < 16; cs++) {                                         \
      float w0 = (WMAT)[(cs * 4 + 0) * 64 + f];                               \
      float w1 = (WMAT)[(cs * 4 + 1) * 64 + f];                               \
      float w2 = (WMAT)[(cs * 4 + 2) * 64 + f];                               \
      float w3 = (WMAT)[(cs * 4 + 3) * 64 + f];                               \
      _Pragma("unroll")                                                       \
      for (int j = 0; j < 16; j++) {                                          \
        const float4 h4 = *(const float4*)&myh[j * 64 + cs * 4];              \
        ACC[j] = fmaf(h4.w, w3, fmaf(h4.z, w2, fmaf(h4.y, w1,                 \
                 fmaf(h4.x, w0, ACC[j]))));                                   \
      }                                                                       \
    }                                                                         \
  }

__global__ __launch_bounds__(256) void k5_attn(
    const float* __restrict__ pos4, const float* __restrict__ qg,
    const float* __restrict__ kg, const float* __restrict__ vg,
    const float* __restrict__ featf, const float* __restrict__ wb,
    const int* __restrict__ knn, float* __restrict__ out)
{
  __shared__ float wl[3 * 4096];   // pe_w2 | at_w1 | at_w2   (48 KB)
  __shared__ float hb[4][1024];    // per-wave 16x64 hidden   (16 KB)
  for (int i = threadIdx.x; i < 3 * 4096; i += 256) wl[i] = wb[W_PE2 + i];
  __syncthreads();
  const int wid = threadIdx.x >> 6;
  const int f = threadIdx.x & 63;
  const int p = blockIdx.x * 4 + wid;
  const int ps = __builtin_amdgcn_readfirstlane(p);
  float* myh = hb[wid];

  float qf    = qg[p * 64 + f];
  float resid = featf[p * 64 + f];
  float pw10 = wb[W_PE1 + f], pw11 = wb[W_PE1 + 64 + f], pw12 = wb[W_PE1 + 128 + f];
  float pb1 = wb[B_PE1 + f], pb2 = wb[B_PE2 + f];
  float ab1 = wb[B_AT1 + f], ab2 = wb[B_AT2 + f], obf = wb[B_OUT + f];
  const float* pp = pos4 + ps * 4;
  float pnx = pp[0], pny = pp[1], pnz = pp[2];
  const int* ip = knn + ps * 16;
  int jj[16];
#pragma unroll
  for (int u = 0; u < 4; u++) {
    int4 t4 = ((const int4*)ip)[u];
    jj[u * 4 + 0] = t4.x; jj[u * 4 + 1] = t4.y;
    jj[u * 4 + 2] = t4.z; jj[u * 4 + 3] = t4.w;
  }
  // phase A: posenc hidden h1 = relu(gpos @ pe_w1 + pe_b1)
#pragma unroll
  for (int j = 0; j < 16; j++) {
    const float* np_ = pos4 + jj[j] * 4;
    float gx = np_[0] - pnx, gy = np_[1] - pny, gz = np_[2] - pnz;
    float h1 = fmaf(gz, pw12, fmaf(gy, pw11, fmaf(gx, pw10, pb1)));
    myh[j * 64 + f] = fmaxf(h1, 0.f);
  }
  __syncthreads();
  float pe[16];
  MATVEC(wl, pb2, pe);                       // posenc = h1 @ pe_w2 + pe_b2
  // phase C: hh = q - k + posenc ; vpe = v + posenc
  float vpe[16];
#pragma unroll
  for (int j = 0; j < 16; j++) {
    float kf = kg[jj[j] * 64 + f];
    float vf = vg[jj[j] * 64 + f];
    vpe[j] = vf + pe[j];
    myh[j * 64 + f] = (qf - kf) + pe[j];
  }
  __syncthreads();
  float hid[16];
  MATVEC(wl + 4096, ab1, hid);               // hh @ at_w1 + at_b1
#pragma unroll
  for (int j = 0; j < 16; j++) myh[j * 64 + f] = fmaxf(hid[j], 0.f);
  __syncthreads();
  float lg[16];
  MATVEC(wl + 8192, ab2, lg);                // logits = relu(.) @ at_w2 + at_b2
  // per-channel softmax over 16 neighbors (axis=-2), scale 1/sqrt(64)
  float mx = lg[0];
#pragma unroll
  for (int j = 1; j < 16; j++) mx = fmaxf(mx, lg[j]);
  float ssum = 0.f;
#pragma unroll
  for (int j = 0; j < 16; j++) {
    float e = __expf((lg[j] - mx) * 0.125f);
    lg[j] = e; ssum += e;
  }
  float inv = 1.0f / ssum;
  float res = 0.f;
#pragma unroll
  for (int j = 0; j < 16; j++) res = fmaf(lg[j], vpe[j], res);
  res *= inv;
  // output projection: out = res @ out_w + out_b + features
  __syncthreads();
  myh[f] = res;
  __syncthreads();
  const float* ow = wb + W_OUT;
  float o = obf;
#pragma unroll
  for (int cs = 0; cs < 16; cs++) {
    float w0 = ow[(cs * 4 + 0) * 64 + f];
    float w1 = ow[(cs * 4 + 1) * 64 + f];
    float w2 = ow[(cs * 4 + 2) * 64 + f];
    float w3 = ow[(cs * 4 + 3) * 64 + f];
    const float4 r4 = *(const float4*)&myh[cs * 4];
    o = fmaf(r4.w, w3, fmaf(r4.z, w2, fmaf(r4.y, w1, fmaf(r4.x, w0, o))));
  }
  out[p * 64 + f] = o + resid;
}

// ============================ launcher ========================================
extern "C" void kernel_launch(void* const* d_in, const int* in_sizes, int n_in,
                              void* d_out, int out_size, void* d_ws, size_t ws_size,
                              hipStream_t stream)
{
  (void)in_sizes; (void)n_in; (void)out_size; (void)ws_size;
  const float* pos   = (const float*)d_in[0];
  const float* feat  = (const float*)d_in[1];
  const float* emb_w = (const float*)d_in[2];
  const float* emb_b = (const float*)d_in[3];
  const float* wq    = (const float*)d_in[4];
  const float* wk    = (const float*)d_in[5];
  const float* wv    = (const float*)d_in[6];
  const float* pe_w1 = (const float*)d_in[7];
  const float* pe_b1 = (const float*)d_in[8];
  const float* pe_w2 = (const float*)d_in[9];
  const float* pe_b2 = (const float*)d_in[10];
  const float* at_w1 = (const float*)d_in[11];
  const float* at_b1 = (const float*)d_in[12];
  const float* at_w2 = (const float*)d_in[13];
  const float* at_b2 = (const float*)d_in[14];
  const float* out_w = (const float*)d_in[15];
  const float* out_b = (const float*)d_in[16];
  float* ws = (float*)d_ws;

  k0_stage<<<195, 256, 0, stream>>>(pos, emb_w, emb_b, wq, wk, wv,
      pe_w1, pe_b1, pe_w2, pe_b2, at_w1, at_b1, at_w2, at_b2, out_w, out_b, ws);
  dim3 g1(BB, NN / 64, SPL);
  k1_knn<<<g1, 64, 0, stream>>>(ws + POS4_OFF, (unsigned*)ws + PART_OFF);
  k2_merge<<<NPTS / 256, 256, 0, stream>>>((unsigned*)ws + PART_OFF,
                                           (int*)ws + IDX_OFF);
  k3_emb<<<NPTS / 128, 256, 0, stream>>>(feat, ws + WBUF_OFF, ws + XB_OFF);
  k4_qkv<<<NPTS / 64, 256, 0, stream>>>(ws + XB_OFF, ws + WBUF_OFF,
                                        ws + QB_OFF, ws + KB_OFF, ws + VB_OFF);
  k5_attn<<<NPTS / 4, 256, 0, stream>>>(ws + POS4_OFF, ws + QB_OFF, ws + KB_OFF,
      ws + VB_OFF, feat, ws + WBUF_OFF, (int*)ws + IDX_OFF, (float*)d_out);
}

// Round 3
// 398.256 us; speedup vs baseline: 1.6961x; 1.6961x over previous
//
#include <hip/hip_runtime.h>
#include <hip/hip_bf16.h>

#define BB 2
#define NN 8192
#define SPL 16
#define CAND (NN/SPL)
#define NPTS (BB*NN)

// ---- workspace layout (units: 4-byte words), total ~18.26 MB ----
#define POS4_OFF 0u
#define WBUF_OFF 65536u
#define XB_OFF   (WBUF_OFF + 33792u)
#define PART_OFF XB_OFF        /* PART (16 MB) spans XB..VB; dead after k2 */
#define QB_OFF   (XB_OFF + 1048576u)
#define KB_OFF   (QB_OFF + 1048576u)
#define VB_OFF   (KB_OFF + 1048576u)
#define IDX_OFF  (VB_OFF + 1048576u)
#define WT_OFF   (IDX_OFF + 262144u)   /* 4 mats x 4096 bf16 = 8192 words */

// ---- wbuf internal offsets (words) ----
#define W_EMB 0
#define W_Q   4096
#define W_K   8192
#define W_V   12288
#define W_PE2 16384
#define W_AT1 20480
#define W_AT2 24576
#define W_OUT 28672
#define W_PE1 32768
#define B_EMB 32960
#define B_PE1 33024
#define B_PE2 33088
#define B_AT1 33152
#define B_AT2 33216
#define B_OUT 33280

typedef __attribute__((ext_vector_type(8))) short bf16x8;
typedef __attribute__((ext_vector_type(4))) float f32x4;

__device__ inline unsigned short f2bf(float x) {
  __hip_bfloat16 b = __float2bfloat16(x);
  return *(unsigned short*)&b;
}

// column-block rotate swizzle: h[j][c] stored at col HCOL(c,j); keeps the 8
// consecutive k of an A-fragment contiguous & 16B-aligned, kills the
// stride-128B same-bank pattern on ds_read_b128 A-reads.
#define HCOL(c, j) ((((((c) >> 3) + (j)) & 7) << 3) | ((c) & 7))

// ============================ K0: stage pos4(+|c|^2), weights, bf16-T mats ====
__global__ __launch_bounds__(256) void k0_stage(
    const float* __restrict__ pos,
    const float* __restrict__ emb_w, const float* __restrict__ emb_b,
    const float* __restrict__ wq, const float* __restrict__ wk,
    const float* __restrict__ wv,
    const float* __restrict__ pe_w1, const float* __restrict__ pe_b1,
    const float* __restrict__ pe_w2, const float* __restrict__ pe_b2,
    const float* __restrict__ at_w1, const float* __restrict__ at_b1,
    const float* __restrict__ at_w2, const float* __restrict__ at_b2,
    const float* __restrict__ out_w, const float* __restrict__ out_b,
    float* __restrict__ ws)
{
  int t = blockIdx.x * 256 + threadIdx.x;
  if (t < NPTS) {
    float x = pos[t * 3 + 0], y = pos[t * 3 + 1], z = pos[t * 3 + 2];
    float* o = ws + POS4_OFF + t * 4;
    o[0] = x; o[1] = y; o[2] = z;
    o[3] = fmaf(x, x, fmaf(y, y, z * z));
    return;
  }
  t -= NPTS;
  float* wbuf = ws + WBUF_OFF;
  if (t < 32768) {
    const float* s;
    switch (t >> 12) {
      case 0: s = emb_w; break;
      case 1: s = wq;    break;
      case 2: s = wk;    break;
      case 3: s = wv;    break;
      case 4: s = pe_w2; break;
      case 5: s = at_w1; break;
      case 6: s = at_w2; break;
      default: s = out_w; break;
    }
    wbuf[t] = s[t & 4095];
    return;
  }
  t -= 32768;
  if (t < 192) { wbuf[W_PE1 + t] = pe_w1[t]; return; }
  t -= 192;
  if (t < 384) {
    const float* s;
    switch (t >> 6) {
      case 0: s = emb_b; break;
      case 1: s = pe_b1; break;
      case 2: s = pe_b2; break;
      case 3: s = at_b1; break;
      case 4: s = at_b2; break;
      default: s = out_b; break;
    }
    wbuf[B_EMB + t] = s[t & 63];
    return;
  }
  t -= 384;
  if (t < 16384) {  // bf16 transposed mats: wt[m][f*64+c] = W_m[c*64+f]
    unsigned short* wt = (unsigned short*)(ws + WT_OFF);
    const float* s;
    switch (t >> 12) {
      case 0: s = pe_w2; break;
      case 1: s = at_w1; break;
      case 2: s = at_w2; break;
      default: s = out_w; break;
    }
    int idx = t & 4095, f = idx >> 6, c = idx & 63;
    wt[t] = f2bf(s[c * 64 + f]);
  }
}

// ============================ K1: brute-force KNN (16-way split) ==============
// rank key = d^2 = |c|^2 + |q|^2 - 2 q.c  (>=0), packed (19 dist bits | 13 idx)
__global__ __launch_bounds__(256) void k1_knn(const float* __restrict__ pos4,
                                              unsigned* __restrict__ part)
{
  const int tid = threadIdx.x;
  const int g = blockIdx.x * 256 + tid;         // global query (block within one batch)
  const int s = blockIdx.y;
  const int bu = __builtin_amdgcn_readfirstlane(g >> 13);
  const float4* __restrict__ allp = (const float4*)pos4;
  const float4 q = allp[g];
  const float qx2 = -2.f * q.x, qy2 = -2.f * q.y, qz2 = -2.f * q.z;
  const float sqq = q.w;
  const float4* __restrict__ cand = allp + (bu * NN + s * CAND);
  unsigned m[16];
#pragma unroll
  for (int i = 0; i < 16; i++) m[i] = 0xFFFFFFFFu;
  const unsigned jb = (unsigned)(s * CAND);
#pragma unroll 2
  for (int j = 0; j < CAND; j++) {
    float4 cp = cand[j];                         // wave-uniform -> s_load_dwordx4
    float d2 = fmaf(cp.x, qx2, fmaf(cp.y, qy2, fmaf(cp.z, qz2, cp.w + sqq)));
    d2 = fmaxf(d2, 0.f);
    unsigned pk = (__float_as_uint(d2) & 0xFFFFE000u) | (jb + (unsigned)j);
    if (pk < m[15]) {
      m[15] = pk;
#pragma unroll
      for (int i = 15; i > 0; i--) {
        unsigned a = m[i - 1], c = m[i];
        m[i - 1] = a < c ? a : c;
        m[i]     = a < c ? c : a;
      }
    }
  }
  unsigned base = ((unsigned)g * SPL + (unsigned)s) * 16u;
  uint4* o = (uint4*)(part + base);
  o[0] = make_uint4(m[0], m[1], m[2], m[3]);
  o[1] = make_uint4(m[4], m[5], m[6], m[7]);
  o[2] = make_uint4(m[8], m[9], m[10], m[11]);
  o[3] = make_uint4(m[12], m[13], m[14], m[15]);
}

// ============================ K2: merge 16 sorted 16-lists (bitonic) ==========
__device__ inline void bclean16(unsigned r[16]) {
#pragma unroll
  for (int d = 8; d; d >>= 1) {
#pragma unroll
    for (int i = 0; i < 16; i++) {
      if ((i & d) == 0) {
        unsigned a = r[i], b = r[i + d];
        r[i]     = a < b ? a : b;
        r[i + d] = a < b ? b : a;
      }
    }
  }
}

__global__ __launch_bounds__(256) void k2_merge(const unsigned* __restrict__ part,
                                                int* __restrict__ knn_idx)
{
  const int g = blockIdx.x * 256 + threadIdx.x;
  const uint4* src = (const uint4*)(part + (unsigned)g * (SPL * 16u));
  unsigned run[16];
#pragma unroll
  for (int i = 0; i < 4; i++) {
    uint4 v = src[i];
    run[i*4+0] = v.x; run[i*4+1] = v.y; run[i*4+2] = v.z; run[i*4+3] = v.w;
  }
#pragma unroll
  for (int l = 1; l < SPL; l++) {
    unsigned lst[16];
#pragma unroll
    for (int i = 0; i < 4; i++) {
      uint4 v = src[l * 4 + i];
      lst[i*4+0] = v.x; lst[i*4+1] = v.y; lst[i*4+2] = v.z; lst[i*4+3] = v.w;
    }
#pragma unroll
    for (int i = 0; i < 16; i++) {        // min(a_i, rev_b_i): lower half of merge
      unsigned b = lst[15 - i];
      run[i] = run[i] < b ? run[i] : b;
    }
    bclean16(run);                        // bitonic -> sorted
  }
  const int base = (g >> 13) * NN;
  int outv[16];
#pragma unroll
  for (int i = 0; i < 16; i++) outv[i] = base + (int)(run[i] & 0x1FFFu);
  int4* o = (int4*)(knn_idx + g * 16);
  o[0] = make_int4(outv[0], outv[1], outv[2], outv[3]);
  o[1] = make_int4(outv[4], outv[5], outv[6], outv[7]);
  o[2] = make_int4(outv[8], outv[9], outv[10], outv[11]);
  o[3] = make_int4(outv[12], outv[13], outv[14], outv[15]);
}

// ============================ K3: x = features @ emb_w + emb_b =================
__global__ __launch_bounds__(256) void k3_emb(const float* __restrict__ feat,
                                              const float* __restrict__ wb,
                                              float* __restrict__ xo)
{
  __shared__ float wl[4096];
  for (int i = threadIdx.x; i < 4096; i += 256) wl[i] = wb[W_EMB + i];
  __syncthreads();
  const int col = threadIdx.x & 63;
  const int rg = threadIdx.x >> 6;
  const int row0 = blockIdx.x * 128 + rg * 32;
  const int rowu = __builtin_amdgcn_readfirstlane(row0);
  float acc[32];
  float bias = wb[B_EMB + col];
#pragma unroll
  for (int r = 0; r < 32; r++) acc[r] = bias;
  for (int c = 0; c < 64; c++) {
    float w = wl[c * 64 + col];
    const float* fp = feat + rowu * 64 + c;
#pragma unroll
    for (int r = 0; r < 32; r++) acc[r] = fmaf(fp[r * 64], w, acc[r]);
  }
#pragma unroll
  for (int r = 0; r < 32; r++) xo[(row0 + r) * 64 + col] = acc[r];
}

// ============================ K4: q,k,v = x @ {wq,wk,wv} =======================
__global__ __launch_bounds__(256) void k4_qkv(const float* __restrict__ xb,
                                              const float* __restrict__ wb,
                                              float* __restrict__ qo,
                                              float* __restrict__ ko,
                                              float* __restrict__ vo)
{
  __shared__ float wl[12288];
  for (int i = threadIdx.x; i < 12288; i += 256) wl[i] = wb[W_Q + i];
  __syncthreads();
  const int col = threadIdx.x & 63;
  const int rg = threadIdx.x >> 6;
  const int row0 = blockIdx.x * 64 + rg * 16;
  const int rowu = __builtin_amdgcn_readfirstlane(row0);
  float aq[16], ak[16], av[16];
#pragma unroll
  for (int r = 0; r < 16; r++) { aq[r] = 0.f; ak[r] = 0.f; av[r] = 0.f; }
  for (int c = 0; c < 64; c++) {
    float w0 = wl[c * 64 + col];
    float w1 = wl[4096 + c * 64 + col];
    float w2 = wl[8192 + c * 64 + col];
    const float* fp = xb + rowu * 64 + c;
#pragma unroll
    for (int r = 0; r < 16; r++) {
      float xv = fp[r * 64];
      aq[r] = fmaf(xv, w0, aq[r]);
      ak[r] = fmaf(xv, w1, ak[r]);
      av[r] = fmaf(xv, w2, av[r]);
    }
  }
#pragma unroll
  for (int r = 0; r < 16; r++) {
    qo[(row0 + r) * 64 + col] = aq[r];
    ko[(row0 + r) * 64 + col] = ak[r];
    vo[(row0 + r) * 64 + col] = av[r];
  }
}

// ============================ K5: MFMA fused posenc/attn/softmax/out ==========
// per wave: 8 points serially. h[16x64] lives in per-wave LDS (bf16, swizzled);
// each matvec = 4 N-tiles x 2 K-steps of mfma_f32_16x16x32_bf16.
__device__ inline void mv(const unsigned short* hm, const bf16x8 B[4][2],
                          const float bias[4], int ln, int quad, f32x4 acc[4])
{
  bf16x8 a0 = *(const bf16x8*)(hm + ln * 64 + (((0 * 4 + quad + ln) & 7) << 3));
  bf16x8 a1 = *(const bf16x8*)(hm + ln * 64 + (((1 * 4 + quad + ln) & 7) << 3));
#pragma unroll
  for (int t = 0; t < 4; t++) {
    f32x4 a = {bias[t], bias[t], bias[t], bias[t]};
    a = __builtin_amdgcn_mfma_f32_16x16x32_bf16(a0, B[t][0], a, 0, 0, 0);
    a = __builtin_amdgcn_mfma_f32_16x16x32_bf16(a1, B[t][1], a, 0, 0, 0);
    acc[t] = a;
  }
}

__global__ __launch_bounds__(256) void k5_attn(
    const float* __restrict__ pos4, const float* __restrict__ qg,
    const float* __restrict__ kg, const float* __restrict__ vg,
    const float* __restrict__ featf, const float* __restrict__ wb,
    const unsigned short* __restrict__ wt, const int* __restrict__ knn,
    float* __restrict__ out)
{
  __shared__ unsigned short hma[4][1024];   // per-wave 16x64 bf16 h
  __shared__ unsigned short resm[2048];     // 32 points x 64 bf16 res
  const int tid = threadIdx.x;
  const int wid = tid >> 6, lane = tid & 63;
  const int ln = lane & 15, quad = lane >> 4;
  unsigned short* hm = hma[wid];

  bf16x8 Bf[3][4][2];                       // pe_w2^T | at_w1^T | at_w2^T frags
#pragma unroll
  for (int m = 0; m < 3; m++)
#pragma unroll
    for (int t = 0; t < 4; t++)
#pragma unroll
      for (int ks = 0; ks < 2; ks++)
        Bf[m][t][ks] = *(const bf16x8*)(wt + m * 4096 + (t * 16 + ln) * 64 +
                                        ks * 32 + quad * 8);

  float pw10 = wb[W_PE1 + lane], pw11 = wb[W_PE1 + 64 + lane],
        pw12 = wb[W_PE1 + 128 + lane];
  float pb1 = wb[B_PE1 + lane];
  float bpe[4], ba1[4], ba2[4];
#pragma unroll
  for (int t = 0; t < 4; t++) {
    bpe[t] = wb[B_PE2 + t * 16 + ln];
    ba1[t] = wb[B_AT1 + t * 16 + ln];
    ba2[t] = wb[B_AT2 + t * 16 + ln];
  }

  for (int pp = 0; pp < 8; pp++) {
    const int p = blockIdx.x * 32 + wid * 8 + pp;
    const int ps = __builtin_amdgcn_readfirstlane(p);
    const int4* ip4 = (const int4*)(knn + ps * 16);
    int jj[16];
#pragma unroll
    for (int u = 0; u < 4; u++) {
      int4 t4 = ip4[u];
      jj[u*4+0] = t4.x; jj[u*4+1] = t4.y; jj[u*4+2] = t4.z; jj[u*4+3] = t4.w;
    }
    const float* mp = pos4 + ps * 4;
    float pnx = mp[0], pny = mp[1], pnz = mp[2];
    // h1 = relu(gpos @ pe_w1 + pe_b1): lane = channel c, all 16 j
#pragma unroll
    for (int j = 0; j < 16; j++) {
      const float* np_ = pos4 + jj[j] * 4;
      float h1 = fmaf(np_[2] - pnz, pw12,
                 fmaf(np_[1] - pny, pw11,
                 fmaf(np_[0] - pnx, pw10, pb1)));
      hm[j * 64 + HCOL(lane, j)] = f2bf(fmaxf(h1, 0.f));
    }
    f32x4 accp[4];
    mv(hm, Bf[0], bpe, ln, quad, accp);     // posenc (C-layout: row j, col f)
    // h2 = q - k + pe ; vpe = v + pe
    float vpe[4][4], qv[4];
#pragma unroll
    for (int t = 0; t < 4; t++) qv[t] = qg[p * 64 + t * 16 + ln];
#pragma unroll
    for (int t = 0; t < 4; t++) {
      const int ft = t * 16 + ln;
#pragma unroll
      for (int r = 0; r < 4; r++) {
        const int j = quad * 4 + r;
        float pe = accp[t][r];
        float kf = kg[jj[j] * 64 + ft];
        float vf = vg[jj[j] * 64 + ft];
        vpe[t][r] = vf + pe;
        hm[j * 64 + HCOL(ft, j)] = f2bf(qv[t] - kf + pe);
      }
    }
    f32x4 acch[4];
    mv(hm, Bf[1], ba1, ln, quad, acch);     // hh @ at_w1 + b
#pragma unroll
    for (int t = 0; t < 4; t++)
#pragma unroll
      for (int r = 0; r < 4; r++) {
        const int j = quad * 4 + r;
        hm[j * 64 + HCOL(t * 16 + ln, j)] = f2bf(fmaxf(acch[t][r], 0.f));
      }
    f32x4 lg[4];
    mv(hm, Bf[2], ba2, ln, quad, lg);       // logits
    const int pb = wid * 8 + pp;
#pragma unroll
    for (int t = 0; t < 4; t++) {
      float mx = fmaxf(fmaxf(lg[t][0], lg[t][1]), fmaxf(lg[t][2], lg[t][3]));
      mx = fmaxf(mx, __shfl_xor(mx, 16));
      mx = fmaxf(mx, __shfl_xor(mx, 32));
      float e0 = __expf((lg[t][0] - mx) * 0.125f);
      float e1 = __expf((lg[t][1] - mx) * 0.125f);
      float e2 = __expf((lg[t][2] - mx) * 0.125f);
      float e3 = __expf((lg[t][3] - mx) * 0.125f);
      float ss = (e0 + e1) + (e2 + e3);
      float dt = fmaf(e3, vpe[t][3], fmaf(e2, vpe[t][2],
                 fmaf(e1, vpe[t][1], e0 * vpe[t][0])));
      ss += __shfl_xor(ss, 16); ss += __shfl_xor(ss, 32);
      dt += __shfl_xor(dt, 16); dt += __shfl_xor(dt, 32);
      float res = dt / ss;
      if (quad == 0) resm[pb * 64 + HCOL(t * 16 + ln, pb)] = f2bf(res);
    }
  }
  __syncthreads();
  // epilogue: out = res @ out_w + out_b + features  (2 M-tiles x 4 N-tiles)
  for (int u = wid; u < 8; u += 4) {
    const int mt = u >> 2, nt = u & 3;
    float ob = wb[B_OUT + nt * 16 + ln];
    f32x4 acc = {ob, ob, ob, ob};
    const int row = mt * 16 + ln;
#pragma unroll
    for (int ks = 0; ks < 2; ks++) {
      bf16x8 a = *(const bf16x8*)(resm + row * 64 +
                                  (((ks * 4 + quad + row) & 7) << 3));
      bf16x8 b = *(const bf16x8*)(wt + 3 * 4096 + (nt * 16 + ln) * 64 +
                                  ks * 32 + quad * 8);
      acc = __builtin_amdgcn_mfma_f32_16x16x32_bf16(a, b, acc, 0, 0, 0);
    }
#pragma unroll
    for (int r = 0; r < 4; r++) {
      const int pt = blockIdx.x * 32 + mt * 16 + quad * 4 + r;
      const int f = nt * 16 + ln;
      out[pt * 64 + f] = acc[r] + featf[pt * 64 + f];
    }
  }
}

// ============================ launcher ========================================
extern "C" void kernel_launch(void* const* d_in, const int* in_sizes, int n_in,
                              void* d_out, int out_size, void* d_ws, size_t ws_size,
                              hipStream_t stream)
{
  (void)in_sizes; (void)n_in; (void)out_size; (void)ws_size;
  const float* pos   = (const float*)d_in[0];
  const float* feat  = (const float*)d_in[1];
  const float* emb_w = (const float*)d_in[2];
  const float* emb_b = (const float*)d_in[3];
  const float* wq    = (const float*)d_in[4];
  const float* wk    = (const float*)d_in[5];
  const float* wv    = (const float*)d_in[6];
  const float* pe_w1 = (const float*)d_in[7];
  const float* pe_b1 = (const float*)d_in[8];
  const float* pe_w2 = (const float*)d_in[9];
  const float* pe_b2 = (const float*)d_in[10];
  const float* at_w1 = (const float*)d_in[11];
  const float* at_b1 = (const float*)d_in[12];
  const float* at_w2 = (const float*)d_in[13];
  const float* at_b2 = (const float*)d_in[14];
  const float* out_w = (const float*)d_in[15];
  const float* out_b = (const float*)d_in[16];
  float* ws = (float*)d_ws;

  k0_stage<<<259, 256, 0, stream>>>(pos, emb_w, emb_b, wq, wk, wv,
      pe_w1, pe_b1, pe_w2, pe_b2, at_w1, at_b1, at_w2, at_b2, out_w, out_b, ws);
  dim3 g1(NPTS / 256, SPL);
  k1_knn<<<g1, 256, 0, stream>>>(ws + POS4_OFF, (unsigned*)ws + PART_OFF);
  k2_merge<<<NPTS / 256, 256, 0, stream>>>((unsigned*)ws + PART_OFF,
                                           (int*)ws + IDX_OFF);
  k3_emb<<<NPTS / 128, 256, 0, stream>>>(feat, ws + WBUF_OFF, ws + XB_OFF);
  k4_qkv<<<NPTS / 64, 256, 0, stream>>>(ws + XB_OFF, ws + WBUF_OFF,
                                        ws + QB_OFF, ws + KB_OFF, ws + VB_OFF);
  k5_attn<<<NPTS / 32, 256, 0, stream>>>(ws + POS4_OFF, ws + QB_OFF, ws + KB_OFF,
      ws + VB_OFF, feat, ws + WBUF_OFF, (unsigned short*)(ws + WT_OFF),
      (int*)ws + IDX_OFF, (float*)d_out);
}

// Round 4
// 296.653 us; speedup vs baseline: 2.2770x; 1.3425x over previous
//
#include <hip/hip_runtime.h>
#include <hip/hip_bf16.h>

#define BB 2
#define NN 8192
#define SPL 16
#define CAND (NN/SPL)
#define NPTS (BB*NN)

// ---- workspace layout (units: 4-byte words), total ~18.26 MB ----
#define POS4_OFF 0u
#define WBUF_OFF 65536u
#define XB_OFF   (WBUF_OFF + 33792u)
#define PART_OFF XB_OFF        /* PART (16 MB) spans XB..VB; dead after k2 */
#define QB_OFF   (XB_OFF + 1048576u)
#define KB_OFF   (QB_OFF + 1048576u)
#define VB_OFF   (KB_OFF + 1048576u)
#define IDX_OFF  (VB_OFF + 1048576u)
#define WT_OFF   (IDX_OFF + 262144u)   /* 4 mats x 4096 bf16 = 8192 words */

// ---- wbuf internal offsets (words) ----
#define W_EMB 0
#define W_Q   4096
#define W_K   8192
#define W_V   12288
#define W_PE2 16384
#define W_AT1 20480
#define W_AT2 24576
#define W_OUT 28672
#define W_PE1 32768
#define B_EMB 32960
#define B_PE1 33024
#define B_PE2 33088
#define B_AT1 33152
#define B_AT2 33216
#define B_OUT 33280

typedef __attribute__((ext_vector_type(8))) short bf16x8;
typedef __attribute__((ext_vector_type(4))) float f32x4;

__device__ inline unsigned short f2bf(float x) {
  __hip_bfloat16 b = __float2bfloat16(x);
  return *(unsigned short*)&b;
}

// column-block rotate swizzle for conflict-free ds_read_b128 A-fragments
#define HCOL(c, j) ((((((c) >> 3) + (j)) & 7) << 3) | ((c) & 7))

// ============================ K0: stage pos4(+|c|^2), weights, bf16-T mats ====
__global__ __launch_bounds__(256) void k0_stage(
    const float* __restrict__ pos,
    const float* __restrict__ emb_w, const float* __restrict__ emb_b,
    const float* __restrict__ wq, const float* __restrict__ wk,
    const float* __restrict__ wv,
    const float* __restrict__ pe_w1, const float* __restrict__ pe_b1,
    const float* __restrict__ pe_w2, const float* __restrict__ pe_b2,
    const float* __restrict__ at_w1, const float* __restrict__ at_b1,
    const float* __restrict__ at_w2, const float* __restrict__ at_b2,
    const float* __restrict__ out_w, const float* __restrict__ out_b,
    float* __restrict__ ws)
{
  int t = blockIdx.x * 256 + threadIdx.x;
  if (t < NPTS) {
    float x = pos[t * 3 + 0], y = pos[t * 3 + 1], z = pos[t * 3 + 2];
    float* o = ws + POS4_OFF + t * 4;
    o[0] = x; o[1] = y; o[2] = z;
    o[3] = fmaf(x, x, fmaf(y, y, z * z));
    return;
  }
  t -= NPTS;
  float* wbuf = ws + WBUF_OFF;
  if (t < 32768) {
    const float* s;
    switch (t >> 12) {
      case 0: s = emb_w; break;
      case 1: s = wq;    break;
      case 2: s = wk;    break;
      case 3: s = wv;    break;
      case 4: s = pe_w2; break;
      case 5: s = at_w1; break;
      case 6: s = at_w2; break;
      default: s = out_w; break;
    }
    wbuf[t] = s[t & 4095];
    return;
  }
  t -= 32768;
  if (t < 192) { wbuf[W_PE1 + t] = pe_w1[t]; return; }
  t -= 192;
  if (t < 384) {
    const float* s;
    switch (t >> 6) {
      case 0: s = emb_b; break;
      case 1: s = pe_b1; break;
      case 2: s = pe_b2; break;
      case 3: s = at_b1; break;
      case 4: s = at_b2; break;
      default: s = out_b; break;
    }
    wbuf[B_EMB + t] = s[t & 63];
    return;
  }
  t -= 384;
  if (t < 16384) {  // bf16 transposed mats: wt[m][f*64+c] = W_m[c*64+f]
    unsigned short* wt = (unsigned short*)(ws + WT_OFF);
    const float* s;
    switch (t >> 12) {
      case 0: s = pe_w2; break;
      case 1: s = at_w1; break;
      case 2: s = at_w2; break;
      default: s = out_w; break;
    }
    int idx = t & 4095, f = idx >> 6, c = idx & 63;
    wt[t] = f2bf(s[c * 64 + f]);
  }
}

// ============================ K1: KNN, batch-16 bitonic selection =============
// key = (19 high dist bits | 13-bit idx); per 16 candidates: sort desc (80 CE),
// elementwise-min vs running asc top-16, bitonic clean (32 CE). Branch-free.
__global__ __launch_bounds__(256) void k1_knn(const float* __restrict__ pos4,
                                              unsigned* __restrict__ part)
{
  const int tid = threadIdx.x;
  const int g = blockIdx.x * 256 + tid;
  const int s = blockIdx.y;
  const int bu = __builtin_amdgcn_readfirstlane(g >> 13);
  const float4* __restrict__ allp = (const float4*)pos4;
  const float4 q = allp[g];
  const float qx2 = -2.f * q.x, qy2 = -2.f * q.y, qz2 = -2.f * q.z;
  const float sqq = q.w;
  const float4* __restrict__ cand = allp + (bu * NN + s * CAND);
  unsigned m[16];
#pragma unroll
  for (int i = 0; i < 16; i++) m[i] = 0xFFFFFFFFu;
  const unsigned jb = (unsigned)(s * CAND);
  for (int j0 = 0; j0 < CAND; j0 += 16) {
    unsigned b[16];
#pragma unroll
    for (int i = 0; i < 16; i++) {
      float4 cp = cand[j0 + i];                // wave-uniform -> scalar loads
      float d2 = fmaf(cp.x, qx2, fmaf(cp.y, qy2, fmaf(cp.z, qz2, cp.w + sqq)));
      d2 = fmaxf(d2, 0.f);
      b[i] = (__float_as_uint(d2) & 0xFFFFE000u) | (jb + (unsigned)(j0 + i));
    }
    // bitonic sort b[] DESCENDING (static network -> v_min/v_max only)
#pragma unroll
    for (int k = 2; k <= 16; k <<= 1) {
#pragma unroll
      for (int jj = k >> 1; jj > 0; jj >>= 1) {
#pragma unroll
        for (int i = 0; i < 16; i++) {
          int l = i ^ jj;
          if (l > i) {
            unsigned x = b[i], y = b[l];
            unsigned mn = x < y ? x : y;
            unsigned mx = x < y ? y : x;
            if ((i & k) == 0) { b[i] = mx; b[l] = mn; }
            else              { b[i] = mn; b[l] = mx; }
          }
        }
      }
    }
    // lower half of merge(m asc, b desc) is bitonic; clean 4 stages -> asc
#pragma unroll
    for (int i = 0; i < 16; i++) m[i] = m[i] < b[i] ? m[i] : b[i];
#pragma unroll
    for (int jj = 8; jj > 0; jj >>= 1) {
#pragma unroll
      for (int i = 0; i < 16; i++) {
        if ((i & jj) == 0) {
          int l = i | jj;
          unsigned x = m[i], y = m[l];
          m[i] = x < y ? x : y;
          m[l] = x < y ? y : x;
        }
      }
    }
  }
  unsigned base = ((unsigned)g * SPL + (unsigned)s) * 16u;
  uint4* o = (uint4*)(part + base);
  o[0] = make_uint4(m[0], m[1], m[2], m[3]);
  o[1] = make_uint4(m[4], m[5], m[6], m[7]);
  o[2] = make_uint4(m[8], m[9], m[10], m[11]);
  o[3] = make_uint4(m[12], m[13], m[14], m[15]);
}

// ============================ K2: merge 16 sorted 16-lists (bitonic) ==========
__device__ inline void bclean16(unsigned r[16]) {
#pragma unroll
  for (int d = 8; d; d >>= 1) {
#pragma unroll
    for (int i = 0; i < 16; i++) {
      if ((i & d) == 0) {
        unsigned a = r[i], b = r[i + d];
        r[i]     = a < b ? a : b;
        r[i + d] = a < b ? b : a;
      }
    }
  }
}

__global__ __launch_bounds__(256) void k2_merge(const unsigned* __restrict__ part,
                                                int* __restrict__ knn_idx)
{
  const int g = blockIdx.x * 256 + threadIdx.x;
  const uint4* src = (const uint4*)(part + (unsigned)g * (SPL * 16u));
  unsigned run[16];
#pragma unroll
  for (int i = 0; i < 4; i++) {
    uint4 v = src[i];
    run[i*4+0] = v.x; run[i*4+1] = v.y; run[i*4+2] = v.z; run[i*4+3] = v.w;
  }
#pragma unroll
  for (int l = 1; l < SPL; l++) {
    unsigned lst[16];
#pragma unroll
    for (int i = 0; i < 4; i++) {
      uint4 v = src[l * 4 + i];
      lst[i*4+0] = v.x; lst[i*4+1] = v.y; lst[i*4+2] = v.z; lst[i*4+3] = v.w;
    }
#pragma unroll
    for (int i = 0; i < 16; i++) {
      unsigned b = lst[15 - i];
      run[i] = run[i] < b ? run[i] : b;
    }
    bclean16(run);
  }
  const int base = (g >> 13) * NN;
  int outv[16];
#pragma unroll
  for (int i = 0; i < 16; i++) outv[i] = base + (int)(run[i] & 0x1FFFu);
  int4* o = (int4*)(knn_idx + g * 16);
  o[0] = make_int4(outv[0], outv[1], outv[2], outv[3]);
  o[1] = make_int4(outv[4], outv[5], outv[6], outv[7]);
  o[2] = make_int4(outv[8], outv[9], outv[10], outv[11]);
  o[3] = make_int4(outv[12], outv[13], outv[14], outv[15]);
}

// ============================ K3: x = features @ emb_w + emb_b =================
__global__ __launch_bounds__(256) void k3_emb(const float* __restrict__ feat,
                                              const float* __restrict__ wb,
                                              float* __restrict__ xo)
{
  __shared__ float wl[4096];
  for (int i = threadIdx.x; i < 4096; i += 256) wl[i] = wb[W_EMB + i];
  __syncthreads();
  const int col = threadIdx.x & 63;
  const int rg = threadIdx.x >> 6;
  const int row0 = blockIdx.x * 128 + rg * 32;
  const int rowu = __builtin_amdgcn_readfirstlane(row0);
  float acc[32];
  float bias = wb[B_EMB + col];
#pragma unroll
  for (int r = 0; r < 32; r++) acc[r] = bias;
  for (int c = 0; c < 64; c++) {
    float w = wl[c * 64 + col];
    const float* fp = feat + rowu * 64 + c;
#pragma unroll
    for (int r = 0; r < 32; r++) acc[r] = fmaf(fp[r * 64], w, acc[r]);
  }
#pragma unroll
  for (int r = 0; r < 32; r++) xo[(row0 + r) * 64 + col] = acc[r];
}

// ============================ K4: q,k,v = x @ {wq,wk,wv} =======================
__global__ __launch_bounds__(256) void k4_qkv(const float* __restrict__ xb,
                                              const float* __restrict__ wb,
                                              float* __restrict__ qo,
                                              float* __restrict__ ko,
                                              float* __restrict__ vo)
{
  __shared__ float wl[12288];
  for (int i = threadIdx.x; i < 12288; i += 256) wl[i] = wb[W_Q + i];
  __syncthreads();
  const int col = threadIdx.x & 63;
  const int rg = threadIdx.x >> 6;
  const int row0 = blockIdx.x * 64 + rg * 16;
  const int rowu = __builtin_amdgcn_readfirstlane(row0);
  float aq[16], ak[16], av[16];
#pragma unroll
  for (int r = 0; r < 16; r++) { aq[r] = 0.f; ak[r] = 0.f; av[r] = 0.f; }
  for (int c = 0; c < 64; c++) {
    float w0 = wl[c * 64 + col];
    float w1 = wl[4096 + c * 64 + col];
    float w2 = wl[8192 + c * 64 + col];
    const float* fp = xb + rowu * 64 + c;
#pragma unroll
    for (int r = 0; r < 16; r++) {
      float xv = fp[r * 64];
      aq[r] = fmaf(xv, w0, aq[r]);
      ak[r] = fmaf(xv, w1, ak[r]);
      av[r] = fmaf(xv, w2, av[r]);
    }
  }
#pragma unroll
  for (int r = 0; r < 16; r++) {
    qo[(row0 + r) * 64 + col] = aq[r];
    ko[(row0 + r) * 64 + col] = ak[r];
    vo[(row0 + r) * 64 + col] = av[r];
  }
}

// ============================ K5: MFMA fused posenc/attn/softmax/out ==========
__device__ inline void mv(const unsigned short* hm, const bf16x8 B[4][2],
                          const float bias[4], int ln, int quad, f32x4 acc[4])
{
  bf16x8 a0 = *(const bf16x8*)(hm + ln * 64 + (((0 * 4 + quad + ln) & 7) << 3));
  bf16x8 a1 = *(const bf16x8*)(hm + ln * 64 + (((1 * 4 + quad + ln) & 7) << 3));
#pragma unroll
  for (int t = 0; t < 4; t++) {
    f32x4 a = {bias[t], bias[t], bias[t], bias[t]};
    a = __builtin_amdgcn_mfma_f32_16x16x32_bf16(a0, B[t][0], a, 0, 0, 0);
    a = __builtin_amdgcn_mfma_f32_16x16x32_bf16(a1, B[t][1], a, 0, 0, 0);
    acc[t] = a;
  }
}

__global__ __launch_bounds__(256) void k5_attn(
    const float* __restrict__ pos4, const float* __restrict__ qg,
    const float* __restrict__ kg, const float* __restrict__ vg,
    const float* __restrict__ featf, const float* __restrict__ wb,
    const unsigned short* __restrict__ wt, const int* __restrict__ knn,
    float* __restrict__ out)
{
  __shared__ unsigned short hma[4][1024];   // per-wave 16x64 bf16 h
  __shared__ unsigned short resm[2048];     // 32 points x 64 bf16 res
  const int tid = threadIdx.x;
  const int wid = tid >> 6, lane = tid & 63;
  const int ln = lane & 15, quad = lane >> 4;
  unsigned short* hm = hma[wid];

  bf16x8 Bf[3][4][2];                       // pe_w2^T | at_w1^T | at_w2^T frags
#pragma unroll
  for (int m = 0; m < 3; m++)
#pragma unroll
    for (int t = 0; t < 4; t++)
#pragma unroll
      for (int ks = 0; ks < 2; ks++)
        Bf[m][t][ks] = *(const bf16x8*)(wt + m * 4096 + (t * 16 + ln) * 64 +
                                        ks * 32 + quad * 8);

  float pw10 = wb[W_PE1 + lane], pw11 = wb[W_PE1 + 64 + lane],
        pw12 = wb[W_PE1 + 128 + lane];
  float pb1 = wb[B_PE1 + lane];
  float bpe[4], ba1[4], ba2[4];
#pragma unroll
  for (int t = 0; t < 4; t++) {
    bpe[t] = wb[B_PE2 + t * 16 + ln];
    ba1[t] = wb[B_AT1 + t * 16 + ln];
    ba2[t] = wb[B_AT2 + t * 16 + ln];
  }

  for (int pp = 0; pp < 8; pp++) {
    const int p = blockIdx.x * 32 + wid * 8 + pp;
    const int ps = __builtin_amdgcn_readfirstlane(p);
    const int4* ip4 = (const int4*)(knn + ps * 16);
    int jj[16];
#pragma unroll
    for (int u = 0; u < 4; u++) {
      int4 t4 = ip4[u];
      jj[u*4+0] = t4.x; jj[u*4+1] = t4.y; jj[u*4+2] = t4.z; jj[u*4+3] = t4.w;
    }
    const float* mp = pos4 + ps * 4;
    float pnx = mp[0], pny = mp[1], pnz = mp[2];
#pragma unroll
    for (int j = 0; j < 16; j++) {
      const float* np_ = pos4 + jj[j] * 4;
      float h1 = fmaf(np_[2] - pnz, pw12,
                 fmaf(np_[1] - pny, pw11,
                 fmaf(np_[0] - pnx, pw10, pb1)));
      hm[j * 64 + HCOL(lane, j)] = f2bf(fmaxf(h1, 0.f));
    }
    f32x4 accp[4];
    mv(hm, Bf[0], bpe, ln, quad, accp);     // posenc
    float vpe[4][4], qv[4];
#pragma unroll
    for (int t = 0; t < 4; t++) qv[t] = qg[p * 64 + t * 16 + ln];
#pragma unroll
    for (int t = 0; t < 4; t++) {
      const int ft = t * 16 + ln;
#pragma unroll
      for (int r = 0; r < 4; r++) {
        const int j = quad * 4 + r;
        float pe = accp[t][r];
        float kf = kg[jj[j] * 64 + ft];
        float vf = vg[jj[j] * 64 + ft];
        vpe[t][r] = vf + pe;
        hm[j * 64 + HCOL(ft, j)] = f2bf(qv[t] - kf + pe);
      }
    }
    f32x4 acch[4];
    mv(hm, Bf[1], ba1, ln, quad, acch);     // hh @ at_w1 + b
#pragma unroll
    for (int t = 0; t < 4; t++)
#pragma unroll
      for (int r = 0; r < 4; r++) {
        const int j = quad * 4 + r;
        hm[j * 64 + HCOL(t * 16 + ln, j)] = f2bf(fmaxf(acch[t][r], 0.f));
      }
    f32x4 lg[4];
    mv(hm, Bf[2], ba2, ln, quad, lg);       // logits
    const int pb = wid * 8 + pp;
#pragma unroll
    for (int t = 0; t < 4; t++) {
      float mx = fmaxf(fmaxf(lg[t][0], lg[t][1]), fmaxf(lg[t][2], lg[t][3]));
      mx = fmaxf(mx, __shfl_xor(mx, 16));
      mx = fmaxf(mx, __shfl_xor(mx, 32));
      float e0 = __expf((lg[t][0] - mx) * 0.125f);
      float e1 = __expf((lg[t][1] - mx) * 0.125f);
      float e2 = __expf((lg[t][2] - mx) * 0.125f);
      float e3 = __expf((lg[t][3] - mx) * 0.125f);
      float ss = (e0 + e1) + (e2 + e3);
      float dt = fmaf(e3, vpe[t][3], fmaf(e2, vpe[t][2],
                 fmaf(e1, vpe[t][1], e0 * vpe[t][0])));
      ss += __shfl_xor(ss, 16); ss += __shfl_xor(ss, 32);
      dt += __shfl_xor(dt, 16); dt += __shfl_xor(dt, 32);
      float res = dt / ss;
      if (quad == 0) resm[pb * 64 + HCOL(t * 16 + ln, pb)] = f2bf(res);
    }
  }
  __syncthreads();
  for (int u = wid; u < 8; u += 4) {
    const int mt = u >> 2, nt = u & 3;
    float ob = wb[B_OUT + nt * 16 + ln];
    f32x4 acc = {ob, ob, ob, ob};
    const int row = mt * 16 + ln;
#pragma unroll
    for (int ks = 0; ks < 2; ks++) {
      bf16x8 a = *(const bf16x8*)(resm + row * 64 +
                                  (((ks * 4 + quad + row) & 7) << 3));
      bf16x8 b = *(const bf16x8*)(wt + 3 * 4096 + (nt * 16 + ln) * 64 +
                                  ks * 32 + quad * 8);
      acc = __builtin_amdgcn_mfma_f32_16x16x32_bf16(a, b, acc, 0, 0, 0);
    }
#pragma unroll
    for (int r = 0; r < 4; r++) {
      const int pt = blockIdx.x * 32 + mt * 16 + quad * 4 + r;
      const int f = nt * 16 + ln;
      out[pt * 64 + f] = acc[r] + featf[pt * 64 + f];
    }
  }
}

// ============================ launcher ========================================
extern "C" void kernel_launch(void* const* d_in, const int* in_sizes, int n_in,
                              void* d_out, int out_size, void* d_ws, size_t ws_size,
                              hipStream_t stream)
{
  (void)in_sizes; (void)n_in; (void)out_size; (void)ws_size;
  const float* pos   = (const float*)d_in[0];
  const float* feat  = (const float*)d_in[1];
  const float* emb_w = (const float*)d_in[2];
  const float* emb_b = (const float*)d_in[3];
  const float* wq    = (const float*)d_in[4];
  const float* wk    = (const float*)d_in[5];
  const float* wv    = (const float*)d_in[6];
  const float* pe_w1 = (const float*)d_in[7];
  const float* pe_b1 = (const float*)d_in[8];
  const float* pe_w2 = (const float*)d_in[9];
  const float* pe_b2 = (const float*)d_in[10];
  const float* at_w1 = (const float*)d_in[11];
  const float* at_b1 = (const float*)d_in[12];
  const float* at_w2 = (const float*)d_in[13];
  const float* at_b2 = (const float*)d_in[14];
  const float* out_w = (const float*)d_in[15];
  const float* out_b = (const float*)d_in[16];
  float* ws = (float*)d_ws;

  k0_stage<<<259, 256, 0, stream>>>(pos, emb_w, emb_b, wq, wk, wv,
      pe_w1, pe_b1, pe_w2, pe_b2, at_w1, at_b1, at_w2, at_b2, out_w, out_b, ws);
  dim3 g1(NPTS / 256, SPL);
  k1_knn<<<g1, 256, 0, stream>>>(ws + POS4_OFF, (unsigned*)ws + PART_OFF);
  k2_merge<<<NPTS / 256, 256, 0, stream>>>((unsigned*)ws + PART_OFF,
                                           (int*)ws + IDX_OFF);
  k3_emb<<<NPTS / 128, 256, 0, stream>>>(feat, ws + WBUF_OFF, ws + XB_OFF);
  k4_qkv<<<NPTS / 64, 256, 0, stream>>>(ws + XB_OFF, ws + WBUF_OFF,
                                        ws + QB_OFF, ws + KB_OFF, ws + VB_OFF);
  k5_attn<<<NPTS / 32, 256, 0, stream>>>(ws + POS4_OFF, ws + QB_OFF, ws + KB_OFF,
      ws + VB_OFF, feat, ws + WBUF_OFF, (unsigned short*)(ws + WT_OFF),
      (int*)ws + IDX_OFF, (float*)d_out);
}

// Round 5
// 265.913 us; speedup vs baseline: 2.5403x; 1.1156x over previous
//
#include <hip/hip_runtime.h>
#include <hip/hip_bf16.h>

#define BB 2
#define NN 8192
#define SPL 16
#define CAND (NN/SPL)
#define NPTS (BB*NN)

// ---- workspace layout (units: 4-byte words), total ~18.26 MB ----
#define POS4_OFF 0u
#define WBUF_OFF 65536u
#define XB_OFF   (WBUF_OFF + 33792u)
#define PART_OFF XB_OFF        /* PART (16.7MB, [256][NPTS]) dead after k2 */
#define QB_OFF   (XB_OFF + 1048576u)
#define KB_OFF   (QB_OFF + 1048576u)
#define VB_OFF   (KB_OFF + 1048576u)
#define IDX_OFF  (VB_OFF + 1048576u)
#define WT_OFF   (IDX_OFF + 262144u)   /* 4 mats x 4096 bf16 = 8192 words */

// ---- wbuf internal offsets (words) ----
#define W_EMB 0
#define W_Q   4096
#define W_K   8192
#define W_V   12288
#define W_PE2 16384
#define W_AT1 20480
#define W_AT2 24576
#define W_OUT 28672
#define W_PE1 32768
#define B_EMB 32960
#define B_PE1 33024
#define B_PE2 33088
#define B_AT1 33152
#define B_AT2 33216
#define B_OUT 33280

typedef __attribute__((ext_vector_type(8))) short bf16x8;
typedef __attribute__((ext_vector_type(4))) float f32x4;

__device__ __forceinline__ unsigned umn(unsigned a, unsigned b) {
#if __has_builtin(__builtin_elementwise_min)
  return __builtin_elementwise_min(a, b);
#else
  return a < b ? a : b;
#endif
}
__device__ __forceinline__ unsigned umx(unsigned a, unsigned b) {
#if __has_builtin(__builtin_elementwise_max)
  return __builtin_elementwise_max(a, b);
#else
  return a < b ? b : a;
#endif
}

__device__ inline unsigned short f2bf(float x) {
  __hip_bfloat16 b = __float2bfloat16(x);
  return *(unsigned short*)&b;
}

// column-block rotate swizzle for conflict-free ds_read_b128 A-fragments
#define HCOL(c, j) ((((((c) >> 3) + (j)) & 7) << 3) | ((c) & 7))

// ============================ K0: stage pos4(+|c|^2), weights, bf16-T mats ====
__global__ __launch_bounds__(256) void k0_stage(
    const float* __restrict__ pos,
    const float* __restrict__ emb_w, const float* __restrict__ emb_b,
    const float* __restrict__ wq, const float* __restrict__ wk,
    const float* __restrict__ wv,
    const float* __restrict__ pe_w1, const float* __restrict__ pe_b1,
    const float* __restrict__ pe_w2, const float* __restrict__ pe_b2,
    const float* __restrict__ at_w1, const float* __restrict__ at_b1,
    const float* __restrict__ at_w2, const float* __restrict__ at_b2,
    const float* __restrict__ out_w, const float* __restrict__ out_b,
    float* __restrict__ ws)
{
  int t = blockIdx.x * 256 + threadIdx.x;
  if (t < NPTS) {
    float x = pos[t * 3 + 0], y = pos[t * 3 + 1], z = pos[t * 3 + 2];
    float* o = ws + POS4_OFF + t * 4;
    o[0] = x; o[1] = y; o[2] = z;
    o[3] = fmaf(x, x, fmaf(y, y, z * z));
    return;
  }
  t -= NPTS;
  float* wbuf = ws + WBUF_OFF;
  if (t < 32768) {
    const float* s;
    switch (t >> 12) {
      case 0: s = emb_w; break;
      case 1: s = wq;    break;
      case 2: s = wk;    break;
      case 3: s = wv;    break;
      case 4: s = pe_w2; break;
      case 5: s = at_w1; break;
      case 6: s = at_w2; break;
      default: s = out_w; break;
    }
    wbuf[t] = s[t & 4095];
    return;
  }
  t -= 32768;
  if (t < 192) { wbuf[W_PE1 + t] = pe_w1[t]; return; }
  t -= 192;
  if (t < 384) {
    const float* s;
    switch (t >> 6) {
      case 0: s = emb_b; break;
      case 1: s = pe_b1; break;
      case 2: s = pe_b2; break;
      case 3: s = at_b1; break;
      case 4: s = at_b2; break;
      default: s = out_b; break;
    }
    wbuf[B_EMB + t] = s[t & 63];
    return;
  }
  t -= 384;
  if (t < 16384) {  // bf16 transposed mats: wt[m][f*64+c] = W_m[c*64+f]
    unsigned short* wt = (unsigned short*)(ws + WT_OFF);
    const float* s;
    switch (t >> 12) {
      case 0: s = pe_w2; break;
      case 1: s = at_w1; break;
      case 2: s = at_w2; break;
      default: s = out_w; break;
    }
    int idx = t & 4095, f = idx >> 6, c = idx & 63;
    wt[t] = f2bf(s[c * 64 + f]);
  }
}

// ============================ K1: KNN, batch-16 OEMS selection ================
// key = (19 high dist bits | 13-bit idx). Per 16 candidates: Batcher odd-even
// mergesort DESC (63 CE), elementwise-min vs running asc top-16 (16),
// 4-stage bitonic clean (32 CE). Branch-free, pure v_min_u32/v_max_u32.
// part layout TRANSPOSED: part[(s*16+i)*NPTS + g] -> coalesced stores/loads.
__global__ __launch_bounds__(256) void k1_knn(const float* __restrict__ pos4,
                                              unsigned* __restrict__ part)
{
  const int tid = threadIdx.x;
  const int g = blockIdx.x * 256 + tid;
  const int s = blockIdx.y;
  const int bu = __builtin_amdgcn_readfirstlane(g >> 13);
  const float4* __restrict__ allp = (const float4*)pos4;
  const float4 q = allp[g];
  const float qx2 = -2.f * q.x, qy2 = -2.f * q.y, qz2 = -2.f * q.z;
  const float sqq = q.w + 1e-5f;     // bias keeps d2>0 under rounding: no fmax
  const float4* __restrict__ cand = allp + (bu * NN + s * CAND);
  unsigned m[16];
#pragma unroll
  for (int i = 0; i < 16; i++) m[i] = 0xFFFFFFFFu;
  const unsigned jb = (unsigned)(s * CAND);

  // Batcher odd-even mergesort network for n=16 (63 comparators)
  constexpr int OE[63][2] = {
    {0,1},{2,3},{4,5},{6,7},{8,9},{10,11},{12,13},{14,15},
    {0,2},{1,3},{4,6},{5,7},{8,10},{9,11},{12,14},{13,15},
    {1,2},{5,6},{9,10},{13,14},
    {0,4},{1,5},{2,6},{3,7},{8,12},{9,13},{10,14},{11,15},
    {2,4},{3,5},{10,12},{11,13},
    {1,2},{3,4},{5,6},{9,10},{11,12},{13,14},
    {0,8},{1,9},{2,10},{3,11},{4,12},{5,13},{6,14},{7,15},
    {4,8},{5,9},{6,10},{7,11},
    {2,4},{3,5},{6,8},{7,9},{10,12},{11,13},
    {1,2},{3,4},{5,6},{7,8},{9,10},{11,12},{13,14}
  };

  for (int j0 = 0; j0 < CAND; j0 += 16) {
    unsigned b[16];
#pragma unroll
    for (int i = 0; i < 16; i++) {
      float4 cp = cand[j0 + i];                // wave-uniform -> scalar loads
      float d2 = fmaf(cp.x, qx2, fmaf(cp.y, qy2, fmaf(cp.z, qz2, cp.w + sqq)));
      b[i] = (__float_as_uint(d2) & 0xFFFFE000u) | (jb + (unsigned)(j0 + i));
    }
    // sort b DESC via OEMS (desc CE: low idx gets max)
#pragma unroll
    for (int c = 0; c < 63; c++) {
      const int x = OE[c][0], y = OE[c][1];
      unsigned lo = umn(b[x], b[y]);
      unsigned hi = umx(b[x], b[y]);
      b[x] = hi; b[y] = lo;
    }
    // lower half of merge(m asc, b desc), then bitonic clean -> asc
#pragma unroll
    for (int i = 0; i < 16; i++) m[i] = umn(m[i], b[i]);
#pragma unroll
    for (int d = 8; d; d >>= 1) {
#pragma unroll
      for (int i = 0; i < 16; i++) {
        if ((i & d) == 0) {
          const int l = i | d;
          unsigned lo = umn(m[i], m[l]);
          unsigned hi = umx(m[i], m[l]);
          m[i] = lo; m[l] = hi;
        }
      }
    }
  }
#pragma unroll
  for (int i = 0; i < 16; i++)
    part[(unsigned)(s * 16 + i) * NPTS + (unsigned)g] = m[i];
}

// ============================ K2: merge 16 sorted 16-lists (coalesced) ========
__global__ __launch_bounds__(256) void k2_merge(const unsigned* __restrict__ part,
                                                int* __restrict__ knn_idx)
{
  const int g = blockIdx.x * 256 + threadIdx.x;
  unsigned run[16];
#pragma unroll
  for (int i = 0; i < 16; i++) run[i] = part[i * NPTS + g];
#pragma unroll
  for (int l = 1; l < SPL; l++) {
#pragma unroll
    for (int i = 0; i < 16; i++)       // min(run[i], rev(lst)[i]) : lower half
      run[i] = umn(run[i], part[(l * 16 + 15 - i) * NPTS + g]);
#pragma unroll
    for (int d = 8; d; d >>= 1) {
#pragma unroll
      for (int i = 0; i < 16; i++) {
        if ((i & d) == 0) {
          const int l2 = i | d;
          unsigned lo = umn(run[i], run[l2]);
          unsigned hi = umx(run[i], run[l2]);
          run[i] = lo; run[l2] = hi;
        }
      }
    }
  }
  const int base = (g >> 13) * NN;
  int outv[16];
#pragma unroll
  for (int i = 0; i < 16; i++) outv[i] = base + (int)(run[i] & 0x1FFFu);
  int4* o = (int4*)(knn_idx + g * 16);
  o[0] = make_int4(outv[0], outv[1], outv[2], outv[3]);
  o[1] = make_int4(outv[4], outv[5], outv[6], outv[7]);
  o[2] = make_int4(outv[8], outv[9], outv[10], outv[11]);
  o[3] = make_int4(outv[12], outv[13], outv[14], outv[15]);
}

// ============================ K3: x = features @ emb_w + emb_b =================
__global__ __launch_bounds__(256) void k3_emb(const float* __restrict__ feat,
                                              const float* __restrict__ wb,
                                              float* __restrict__ xo)
{
  __shared__ float wl[4096];
  for (int i = threadIdx.x; i < 4096; i += 256) wl[i] = wb[W_EMB + i];
  __syncthreads();
  const int col = threadIdx.x & 63;
  const int rg = threadIdx.x >> 6;
  const int row0 = blockIdx.x * 32 + rg * 8;
  const int rowu = __builtin_amdgcn_readfirstlane(row0);
  float acc[8];
  float bias = wb[B_EMB + col];
#pragma unroll
  for (int r = 0; r < 8; r++) acc[r] = bias;
  for (int c = 0; c < 64; c++) {
    float w = wl[c * 64 + col];
    const float* fp = feat + rowu * 64 + c;
#pragma unroll
    for (int r = 0; r < 8; r++) acc[r] = fmaf(fp[r * 64], w, acc[r]);
  }
#pragma unroll
  for (int r = 0; r < 8; r++) xo[(row0 + r) * 64 + col] = acc[r];
}

// ============================ K4: q,k,v = x @ {wq,wk,wv} =======================
__global__ __launch_bounds__(256) void k4_qkv(const float* __restrict__ xb,
                                              const float* __restrict__ wb,
                                              float* __restrict__ qo,
                                              float* __restrict__ ko,
                                              float* __restrict__ vo)
{
  __shared__ float wl[12288];
  for (int i = threadIdx.x; i < 12288; i += 256) wl[i] = wb[W_Q + i];
  __syncthreads();
  const int col = threadIdx.x & 63;
  const int rg = threadIdx.x >> 6;
  const int row0 = blockIdx.x * 32 + rg * 8;
  const int rowu = __builtin_amdgcn_readfirstlane(row0);
  float aq[8], ak[8], av[8];
#pragma unroll
  for (int r = 0; r < 8; r++) { aq[r] = 0.f; ak[r] = 0.f; av[r] = 0.f; }
  for (int c = 0; c < 64; c++) {
    float w0 = wl[c * 64 + col];
    float w1 = wl[4096 + c * 64 + col];
    float w2 = wl[8192 + c * 64 + col];
    const float* fp = xb + rowu * 64 + c;
#pragma unroll
    for (int r = 0; r < 8; r++) {
      float xv = fp[r * 64];
      aq[r] = fmaf(xv, w0, aq[r]);
      ak[r] = fmaf(xv, w1, ak[r]);
      av[r] = fmaf(xv, w2, av[r]);
    }
  }
#pragma unroll
  for (int r = 0; r < 8; r++) {
    qo[(row0 + r) * 64 + col] = aq[r];
    ko[(row0 + r) * 64 + col] = ak[r];
    vo[(row0 + r) * 64 + col] = av[r];
  }
}

// ============================ K5: MFMA fused posenc/attn/softmax/out ==========
__device__ inline void mv(const unsigned short* hm, const bf16x8 B[4][2],
                          const float bias[4], int ln, int quad, f32x4 acc[4])
{
  bf16x8 a0 = *(const bf16x8*)(hm + ln * 64 + (((0 * 4 + quad + ln) & 7) << 3));
  bf16x8 a1 = *(const bf16x8*)(hm + ln * 64 + (((1 * 4 + quad + ln) & 7) << 3));
#pragma unroll
  for (int t = 0; t < 4; t++) {
    f32x4 a = {bias[t], bias[t], bias[t], bias[t]};
    a = __builtin_amdgcn_mfma_f32_16x16x32_bf16(a0, B[t][0], a, 0, 0, 0);
    a = __builtin_amdgcn_mfma_f32_16x16x32_bf16(a1, B[t][1], a, 0, 0, 0);
    acc[t] = a;
  }
}

__global__ __launch_bounds__(256) void k5_attn(
    const float* __restrict__ pos4, const float* __restrict__ qg,
    const float* __restrict__ kg, const float* __restrict__ vg,
    const float* __restrict__ featf, const float* __restrict__ wb,
    const unsigned short* __restrict__ wt, const int* __restrict__ knn,
    float* __restrict__ out)
{
  __shared__ unsigned short hma[4][1024];   // per-wave 16x64 bf16 h
  __shared__ unsigned short resm[2048];     // 32 points x 64 bf16 res
  const int tid = threadIdx.x;
  const int wid = tid >> 6, lane = tid & 63;
  const int ln = lane & 15, quad = lane >> 4;
  unsigned short* hm = hma[wid];

  bf16x8 Bf[3][4][2];                       // pe_w2^T | at_w1^T | at_w2^T frags
#pragma unroll
  for (int m = 0; m < 3; m++)
#pragma unroll
    for (int t = 0; t < 4; t++)
#pragma unroll
      for (int ks = 0; ks < 2; ks++)
        Bf[m][t][ks] = *(const bf16x8*)(wt + m * 4096 + (t * 16 + ln) * 64 +
                                        ks * 32 + quad * 8);

  float pw10 = wb[W_PE1 + lane], pw11 = wb[W_PE1 + 64 + lane],
        pw12 = wb[W_PE1 + 128 + lane];
  float pb1 = wb[B_PE1 + lane];
  float bpe[4], ba1[4], ba2[4];
#pragma unroll
  for (int t = 0; t < 4; t++) {
    bpe[t] = wb[B_PE2 + t * 16 + ln];
    ba1[t] = wb[B_AT1 + t * 16 + ln];
    ba2[t] = wb[B_AT2 + t * 16 + ln];
  }

  for (int pp = 0; pp < 8; pp++) {
    const int p = blockIdx.x * 32 + wid * 8 + pp;
    const int ps = __builtin_amdgcn_readfirstlane(p);
    const int4* ip4 = (const int4*)(knn + ps * 16);
    int jj[16];
#pragma unroll
    for (int u = 0; u < 4; u++) {
      int4 t4 = ip4[u];
      jj[u*4+0] = t4.x; jj[u*4+1] = t4.y; jj[u*4+2] = t4.z; jj[u*4+3] = t4.w;
    }
    const float* mp = pos4 + ps * 4;
    float pnx = mp[0], pny = mp[1], pnz = mp[2];
#pragma unroll
    for (int j = 0; j < 16; j++) {
      const float* np_ = pos4 + jj[j] * 4;
      float h1 = fmaf(np_[2] - pnz, pw12,
                 fmaf(np_[1] - pny, pw11,
                 fmaf(np_[0] - pnx, pw10, pb1)));
      hm[j * 64 + HCOL(lane, j)] = f2bf(fmaxf(h1, 0.f));
    }
    f32x4 accp[4];
    mv(hm, Bf[0], bpe, ln, quad, accp);     // posenc
    float vpe[4][4], qv[4];
#pragma unroll
    for (int t = 0; t < 4; t++) qv[t] = qg[p * 64 + t * 16 + ln];
#pragma unroll
    for (int t = 0; t < 4; t++) {
      const int ft = t * 16 + ln;
#pragma unroll
      for (int r = 0; r < 4; r++) {
        const int j = quad * 4 + r;
        float pe = accp[t][r];
        float kf = kg[jj[j] * 64 + ft];
        float vf = vg[jj[j] * 64 + ft];
        vpe[t][r] = vf + pe;
        hm[j * 64 + HCOL(ft, j)] = f2bf(qv[t] - kf + pe);
      }
    }
    f32x4 acch[4];
    mv(hm, Bf[1], ba1, ln, quad, acch);     // hh @ at_w1 + b
#pragma unroll
    for (int t = 0; t < 4; t++)
#pragma unroll
      for (int r = 0; r < 4; r++) {
        const int j = quad * 4 + r;
        hm[j * 64 + HCOL(t * 16 + ln, j)] = f2bf(fmaxf(acch[t][r], 0.f));
      }
    f32x4 lg[4];
    mv(hm, Bf[2], ba2, ln, quad, lg);       // logits
    const int pb = wid * 8 + pp;
#pragma unroll
    for (int t = 0; t < 4; t++) {
      float mx = fmaxf(fmaxf(lg[t][0], lg[t][1]), fmaxf(lg[t][2], lg[t][3]));
      mx = fmaxf(mx, __shfl_xor(mx, 16));
      mx = fmaxf(mx, __shfl_xor(mx, 32));
      float e0 = __expf((lg[t][0] - mx) * 0.125f);
      float e1 = __expf((lg[t][1] - mx) * 0.125f);
      float e2 = __expf((lg[t][2] - mx) * 0.125f);
      float e3 = __expf((lg[t][3] - mx) * 0.125f);
      float ss = (e0 + e1) + (e2 + e3);
      float dt = fmaf(e3, vpe[t][3], fmaf(e2, vpe[t][2],
                 fmaf(e1, vpe[t][1], e0 * vpe[t][0])));
      ss += __shfl_xor(ss, 16); ss += __shfl_xor(ss, 32);
      dt += __shfl_xor(dt, 16); dt += __shfl_xor(dt, 32);
      float res = dt / ss;
      if (quad == 0) resm[pb * 64 + HCOL(t * 16 + ln, pb)] = f2bf(res);
    }
  }
  __syncthreads();
  for (int u = wid; u < 8; u += 4) {
    const int mt = u >> 2, nt = u & 3;
    float ob = wb[B_OUT + nt * 16 + ln];
    f32x4 acc = {ob, ob, ob, ob};
    const int row = mt * 16 + ln;
#pragma unroll
    for (int ks = 0; ks < 2; ks++) {
      bf16x8 a = *(const bf16x8*)(resm + row * 64 +
                                  (((ks * 4 + quad + row) & 7) << 3));
      bf16x8 b = *(const bf16x8*)(wt + 3 * 4096 + (nt * 16 + ln) * 64 +
                                  ks * 32 + quad * 8);
      acc = __builtin_amdgcn_mfma_f32_16x16x32_bf16(a, b, acc, 0, 0, 0);
    }
#pragma unroll
    for (int r = 0; r < 4; r++) {
      const int pt = blockIdx.x * 32 + mt * 16 + quad * 4 + r;
      const int f = nt * 16 + ln;
      out[pt * 64 + f] = acc[r] + featf[pt * 64 + f];
    }
  }
}

// ============================ launcher ========================================
extern "C" void kernel_launch(void* const* d_in, const int* in_sizes, int n_in,
                              void* d_out, int out_size, void* d_ws, size_t ws_size,
                              hipStream_t stream)
{
  (void)in_sizes; (void)n_in; (void)out_size; (void)ws_size;
  const float* pos   = (const float*)d_in[0];
  const float* feat  = (const float*)d_in[1];
  const float* emb_w = (const float*)d_in[2];
  const float* emb_b = (const float*)d_in[3];
  const float* wq    = (const float*)d_in[4];
  const float* wk    = (const float*)d_in[5];
  const float* wv    = (const float*)d_in[6];
  const float* pe_w1 = (const float*)d_in[7];
  const float* pe_b1 = (const float*)d_in[8];
  const float* pe_w2 = (const float*)d_in[9];
  const float* pe_b2 = (const float*)d_in[10];
  const float* at_w1 = (const float*)d_in[11];
  const float* at_b1 = (const float*)d_in[12];
  const float* at_w2 = (const float*)d_in[13];
  const float* at_b2 = (const float*)d_in[14];
  const float* out_w = (const float*)d_in[15];
  const float* out_b = (const float*)d_in[16];
  float* ws = (float*)d_ws;

  k0_stage<<<259, 256, 0, stream>>>(pos, emb_w, emb_b, wq, wk, wv,
      pe_w1, pe_b1, pe_w2, pe_b2, at_w1, at_b1, at_w2, at_b2, out_w, out_b, ws);
  dim3 g1(NPTS / 256, SPL);
  k1_knn<<<g1, 256, 0, stream>>>(ws + POS4_OFF, (unsigned*)ws + PART_OFF);
  k2_merge<<<NPTS / 256, 256, 0, stream>>>((unsigned*)ws + PART_OFF,
                                           (int*)ws + IDX_OFF);
  k3_emb<<<NPTS / 32, 256, 0, stream>>>(feat, ws + WBUF_OFF, ws + XB_OFF);
  k4_qkv<<<NPTS / 32, 256, 0, stream>>>(ws + XB_OFF, ws + WBUF_OFF,
                                        ws + QB_OFF, ws + KB_OFF, ws + VB_OFF);
  k5_attn<<<NPTS / 32, 256, 0, stream>>>(ws + POS4_OFF, ws + QB_OFF, ws + KB_OFF,
      ws + VB_OFF, feat, ws + WBUF_OFF, (unsigned short*)(ws + WT_OFF),
      (int*)ws + IDX_OFF, (float*)d_out);
}

// Round 6
// 264.629 us; speedup vs baseline: 2.5526x; 1.0049x over previous
//
#include <hip/hip_runtime.h>
#include <hip/hip_bf16.h>

#define BB 2
#define NN 8192
#define SPL 16
#define CAND (NN/SPL)
#define NPTS (BB*NN)

// ---- workspace layout (units: 4-byte words), total ~18.26 MB ----
#define POS4_OFF 0u
#define WBUF_OFF 65536u
#define XB_OFF   (WBUF_OFF + 33792u)
#define PART_OFF XB_OFF        /* PART (16.7MB, [256][NPTS]) dead after k2 */
#define QB_OFF   (XB_OFF + 1048576u)
#define KB_OFF   (QB_OFF + 1048576u)
#define VB_OFF   (KB_OFF + 1048576u)
#define IDX_OFF  (VB_OFF + 1048576u)
#define WT_OFF   (IDX_OFF + 262144u)   /* 4 mats x 4096 bf16 = 8192 words */

// ---- wbuf internal offsets (words) ----
#define W_EMB 0
#define W_Q   4096
#define W_K   8192
#define W_V   12288
#define W_PE2 16384
#define W_AT1 20480
#define W_AT2 24576
#define W_OUT 28672
#define W_PE1 32768
#define B_EMB 32960
#define B_PE1 33024
#define B_PE2 33088
#define B_AT1 33152
#define B_AT2 33216
#define B_OUT 33280

typedef __attribute__((ext_vector_type(8))) short bf16x8;
typedef __attribute__((ext_vector_type(4))) float f32x4;

__device__ __forceinline__ unsigned umn(unsigned a, unsigned b) {
#if __has_builtin(__builtin_elementwise_min)
  return __builtin_elementwise_min(a, b);
#else
  return a < b ? a : b;
#endif
}
__device__ __forceinline__ unsigned umx(unsigned a, unsigned b) {
#if __has_builtin(__builtin_elementwise_max)
  return __builtin_elementwise_max(a, b);
#else
  return a < b ? b : a;
#endif
}

__device__ inline unsigned short f2bf(float x) {
  __hip_bfloat16 b = __float2bfloat16(x);
  return *(unsigned short*)&b;
}

// column-block rotate swizzle for conflict-free ds_read_b128 A-fragments
#define HCOL(c, j) ((((((c) >> 3) + (j)) & 7) << 3) | ((c) & 7))

// ============================ K0: stage pos4(+|c|^2), weights, bf16-T mats ====
__global__ __launch_bounds__(256) void k0_stage(
    const float* __restrict__ pos,
    const float* __restrict__ emb_w, const float* __restrict__ emb_b,
    const float* __restrict__ wq, const float* __restrict__ wk,
    const float* __restrict__ wv,
    const float* __restrict__ pe_w1, const float* __restrict__ pe_b1,
    const float* __restrict__ pe_w2, const float* __restrict__ pe_b2,
    const float* __restrict__ at_w1, const float* __restrict__ at_b1,
    const float* __restrict__ at_w2, const float* __restrict__ at_b2,
    const float* __restrict__ out_w, const float* __restrict__ out_b,
    float* __restrict__ ws)
{
  int t = blockIdx.x * 256 + threadIdx.x;
  if (t < NPTS) {
    float x = pos[t * 3 + 0], y = pos[t * 3 + 1], z = pos[t * 3 + 2];
    float* o = ws + POS4_OFF + t * 4;
    o[0] = x; o[1] = y; o[2] = z;
    o[3] = fmaf(x, x, fmaf(y, y, z * z));
    return;
  }
  t -= NPTS;
  float* wbuf = ws + WBUF_OFF;
  if (t < 32768) {
    const float* s;
    switch (t >> 12) {
      case 0: s = emb_w; break;
      case 1: s = wq;    break;
      case 2: s = wk;    break;
      case 3: s = wv;    break;
      case 4: s = pe_w2; break;
      case 5: s = at_w1; break;
      case 6: s = at_w2; break;
      default: s = out_w; break;
    }
    wbuf[t] = s[t & 4095];
    return;
  }
  t -= 32768;
  if (t < 192) { wbuf[W_PE1 + t] = pe_w1[t]; return; }
  t -= 192;
  if (t < 384) {
    const float* s;
    switch (t >> 6) {
      case 0: s = emb_b; break;
      case 1: s = pe_b1; break;
      case 2: s = pe_b2; break;
      case 3: s = at_b1; break;
      case 4: s = at_b2; break;
      default: s = out_b; break;
    }
    wbuf[B_EMB + t] = s[t & 63];
    return;
  }
  t -= 384;
  if (t < 16384) {  // bf16 transposed mats: wt[m][f*64+c] = W_m[c*64+f]
    unsigned short* wt = (unsigned short*)(ws + WT_OFF);
    const float* s;
    switch (t >> 12) {
      case 0: s = pe_w2; break;
      case 1: s = at_w1; break;
      case 2: s = at_w2; break;
      default: s = out_w; break;
    }
    int idx = t & 4095, f = idx >> 6, c = idx & 63;
    wt[t] = f2bf(s[c * 64 + f]);
  }
}

// ============================ K1: KNN, batch-16 OEMS selection ================
__global__ __launch_bounds__(256) void k1_knn(const float* __restrict__ pos4,
                                              unsigned* __restrict__ part)
{
  const int tid = threadIdx.x;
  const int g = blockIdx.x * 256 + tid;
  const int s = blockIdx.y;
  const int bu = __builtin_amdgcn_readfirstlane(g >> 13);
  const float4* __restrict__ allp = (const float4*)pos4;
  const float4 q = allp[g];
  const float qx2 = -2.f * q.x, qy2 = -2.f * q.y, qz2 = -2.f * q.z;
  const float sqq = q.w + 1e-5f;     // bias keeps d2>0 under rounding: no fmax
  const float4* __restrict__ cand = allp + (bu * NN + s * CAND);
  unsigned m[16];
#pragma unroll
  for (int i = 0; i < 16; i++) m[i] = 0xFFFFFFFFu;
  const unsigned jb = (unsigned)(s * CAND);

  constexpr int OE[63][2] = {
    {0,1},{2,3},{4,5},{6,7},{8,9},{10,11},{12,13},{14,15},
    {0,2},{1,3},{4,6},{5,7},{8,10},{9,11},{12,14},{13,15},
    {1,2},{5,6},{9,10},{13,14},
    {0,4},{1,5},{2,6},{3,7},{8,12},{9,13},{10,14},{11,15},
    {2,4},{3,5},{10,12},{11,13},
    {1,2},{3,4},{5,6},{9,10},{11,12},{13,14},
    {0,8},{1,9},{2,10},{3,11},{4,12},{5,13},{6,14},{7,15},
    {4,8},{5,9},{6,10},{7,11},
    {2,4},{3,5},{6,8},{7,9},{10,12},{11,13},
    {1,2},{3,4},{5,6},{7,8},{9,10},{11,12},{13,14}
  };

  for (int j0 = 0; j0 < CAND; j0 += 16) {
    unsigned b[16];
#pragma unroll
    for (int i = 0; i < 16; i++) {
      float4 cp = cand[j0 + i];                // wave-uniform -> scalar loads
      float d2 = fmaf(cp.x, qx2, fmaf(cp.y, qy2, fmaf(cp.z, qz2, cp.w + sqq)));
      b[i] = (__float_as_uint(d2) & 0xFFFFE000u) | (jb + (unsigned)(j0 + i));
    }
#pragma unroll
    for (int c = 0; c < 63; c++) {
      const int x = OE[c][0], y = OE[c][1];
      unsigned lo = umn(b[x], b[y]);
      unsigned hi = umx(b[x], b[y]);
      b[x] = hi; b[y] = lo;
    }
#pragma unroll
    for (int i = 0; i < 16; i++) m[i] = umn(m[i], b[i]);
#pragma unroll
    for (int d = 8; d; d >>= 1) {
#pragma unroll
      for (int i = 0; i < 16; i++) {
        if ((i & d) == 0) {
          const int l = i | d;
          unsigned lo = umn(m[i], m[l]);
          unsigned hi = umx(m[i], m[l]);
          m[i] = lo; m[l] = hi;
        }
      }
    }
  }
#pragma unroll
  for (int i = 0; i < 16; i++)
    part[(unsigned)(s * 16 + i) * NPTS + (unsigned)g] = m[i];
}

// ============================ K2: merge 16 sorted 16-lists (coalesced) ========
__global__ __launch_bounds__(256) void k2_merge(const unsigned* __restrict__ part,
                                                int* __restrict__ knn_idx)
{
  const int g = blockIdx.x * 256 + threadIdx.x;
  unsigned run[16];
#pragma unroll
  for (int i = 0; i < 16; i++) run[i] = part[i * NPTS + g];
#pragma unroll
  for (int l = 1; l < SPL; l++) {
#pragma unroll
    for (int i = 0; i < 16; i++)
      run[i] = umn(run[i], part[(l * 16 + 15 - i) * NPTS + g]);
#pragma unroll
    for (int d = 8; d; d >>= 1) {
#pragma unroll
      for (int i = 0; i < 16; i++) {
        if ((i & d) == 0) {
          const int l2 = i | d;
          unsigned lo = umn(run[i], run[l2]);
          unsigned hi = umx(run[i], run[l2]);
          run[i] = lo; run[l2] = hi;
        }
      }
    }
  }
  const int base = (g >> 13) * NN;
  int outv[16];
#pragma unroll
  for (int i = 0; i < 16; i++) outv[i] = base + (int)(run[i] & 0x1FFFu);
  int4* o = (int4*)(knn_idx + g * 16);
  o[0] = make_int4(outv[0], outv[1], outv[2], outv[3]);
  o[1] = make_int4(outv[4], outv[5], outv[6], outv[7]);
  o[2] = make_int4(outv[8], outv[9], outv[10], outv[11]);
  o[3] = make_int4(outv[12], outv[13], outv[14], outv[15]);
}

// ============================ K3: x = features @ emb_w + emb_b =================
__global__ __launch_bounds__(256) void k3_emb(const float* __restrict__ feat,
                                              const float* __restrict__ wb,
                                              float* __restrict__ xo)
{
  __shared__ float wl[4096];
  for (int i = threadIdx.x; i < 4096; i += 256) wl[i] = wb[W_EMB + i];
  __syncthreads();
  const int col = threadIdx.x & 63;
  const int rg = threadIdx.x >> 6;
  const int row0 = blockIdx.x * 32 + rg * 8;
  const int rowu = __builtin_amdgcn_readfirstlane(row0);
  float acc[8];
  float bias = wb[B_EMB + col];
#pragma unroll
  for (int r = 0; r < 8; r++) acc[r] = bias;
  for (int c = 0; c < 64; c++) {
    float w = wl[c * 64 + col];
    const float* fp = feat + rowu * 64 + c;
#pragma unroll
    for (int r = 0; r < 8; r++) acc[r] = fmaf(fp[r * 64], w, acc[r]);
  }
#pragma unroll
  for (int r = 0; r < 8; r++) xo[(row0 + r) * 64 + col] = acc[r];
}

// ============================ K4: q,k,v = x @ {wq,wk,wv} =======================
__global__ __launch_bounds__(256) void k4_qkv(const float* __restrict__ xb,
                                              const float* __restrict__ wb,
                                              float* __restrict__ qo,
                                              float* __restrict__ ko,
                                              float* __restrict__ vo)
{
  __shared__ float wl[12288];
  for (int i = threadIdx.x; i < 12288; i += 256) wl[i] = wb[W_Q + i];
  __syncthreads();
  const int col = threadIdx.x & 63;
  const int rg = threadIdx.x >> 6;
  const int row0 = blockIdx.x * 32 + rg * 8;
  const int rowu = __builtin_amdgcn_readfirstlane(row0);
  float aq[8], ak[8], av[8];
#pragma unroll
  for (int r = 0; r < 8; r++) { aq[r] = 0.f; ak[r] = 0.f; av[r] = 0.f; }
  for (int c = 0; c < 64; c++) {
    float w0 = wl[c * 64 + col];
    float w1 = wl[4096 + c * 64 + col];
    float w2 = wl[8192 + c * 64 + col];
    const float* fp = xb + rowu * 64 + c;
#pragma unroll
    for (int r = 0; r < 8; r++) {
      float xv = fp[r * 64];
      aq[r] = fmaf(xv, w0, aq[r]);
      ak[r] = fmaf(xv, w1, ak[r]);
      av[r] = fmaf(xv, w2, av[r]);
    }
  }
#pragma unroll
  for (int r = 0; r < 8; r++) {
    qo[(row0 + r) * 64 + col] = aq[r];
    ko[(row0 + r) * 64 + col] = ak[r];
    vo[(row0 + r) * 64 + col] = av[r];
  }
}

// ============================ K5: MFMA fused posenc/attn/softmax/out ==========
// 4 points per wave (serial), 16 points per block, grid = NPTS/16 = 1024
// blocks -> fills the 128-VGPR residency limit (4 blocks/CU, 4 waves/SIMD).
__device__ inline void mv(const unsigned short* hm, const bf16x8 B[4][2],
                          const float bias[4], int ln, int quad, f32x4 acc[4])
{
  bf16x8 a0 = *(const bf16x8*)(hm + ln * 64 + (((0 * 4 + quad + ln) & 7) << 3));
  bf16x8 a1 = *(const bf16x8*)(hm + ln * 64 + (((1 * 4 + quad + ln) & 7) << 3));
#pragma unroll
  for (int t = 0; t < 4; t++) {
    f32x4 a = {bias[t], bias[t], bias[t], bias[t]};
    a = __builtin_amdgcn_mfma_f32_16x16x32_bf16(a0, B[t][0], a, 0, 0, 0);
    a = __builtin_amdgcn_mfma_f32_16x16x32_bf16(a1, B[t][1], a, 0, 0, 0);
    acc[t] = a;
  }
}

__global__ __launch_bounds__(256) void k5_attn(
    const float* __restrict__ pos4, const float* __restrict__ qg,
    const float* __restrict__ kg, const float* __restrict__ vg,
    const float* __restrict__ featf, const float* __restrict__ wb,
    const unsigned short* __restrict__ wt, const int* __restrict__ knn,
    float* __restrict__ out)
{
  __shared__ unsigned short hma[4][1024];   // per-wave 16x64 bf16 h
  __shared__ unsigned short resm[1024];     // 16 points x 64 bf16 res
  const int tid = threadIdx.x;
  const int wid = tid >> 6, lane = tid & 63;
  const int ln = lane & 15, quad = lane >> 4;
  unsigned short* hm = hma[wid];

  bf16x8 Bf[3][4][2];                       // pe_w2^T | at_w1^T | at_w2^T frags
#pragma unroll
  for (int m = 0; m < 3; m++)
#pragma unroll
    for (int t = 0; t < 4; t++)
#pragma unroll
      for (int ks = 0; ks < 2; ks++)
        Bf[m][t][ks] = *(const bf16x8*)(wt + m * 4096 + (t * 16 + ln) * 64 +
                                        ks * 32 + quad * 8);

  float pw10 = wb[W_PE1 + lane], pw11 = wb[W_PE1 + 64 + lane],
        pw12 = wb[W_PE1 + 128 + lane];
  float pb1 = wb[B_PE1 + lane];
  float bpe[4], ba1[4], ba2[4];
#pragma unroll
  for (int t = 0; t < 4; t++) {
    bpe[t] = wb[B_PE2 + t * 16 + ln];
    ba1[t] = wb[B_AT1 + t * 16 + ln];
    ba2[t] = wb[B_AT2 + t * 16 + ln];
  }

  for (int pp = 0; pp < 4; pp++) {
    const int p = blockIdx.x * 16 + wid * 4 + pp;
    const int ps = __builtin_amdgcn_readfirstlane(p);
    const int4* ip4 = (const int4*)(knn + ps * 16);
    int jj[16];
#pragma unroll
    for (int u = 0; u < 4; u++) {
      int4 t4 = ip4[u];
      jj[u*4+0] = t4.x; jj[u*4+1] = t4.y; jj[u*4+2] = t4.z; jj[u*4+3] = t4.w;
    }
    const float* mp = pos4 + ps * 4;
    float pnx = mp[0], pny = mp[1], pnz = mp[2];
#pragma unroll
    for (int j = 0; j < 16; j++) {
      const float* np_ = pos4 + jj[j] * 4;
      float h1 = fmaf(np_[2] - pnz, pw12,
                 fmaf(np_[1] - pny, pw11,
                 fmaf(np_[0] - pnx, pw10, pb1)));
      hm[j * 64 + HCOL(lane, j)] = f2bf(fmaxf(h1, 0.f));
    }
    f32x4 accp[4];
    mv(hm, Bf[0], bpe, ln, quad, accp);     // posenc
    float vpe[4][4], qv[4];
#pragma unroll
    for (int t = 0; t < 4; t++) qv[t] = qg[p * 64 + t * 16 + ln];
#pragma unroll
    for (int t = 0; t < 4; t++) {
      const int ft = t * 16 + ln;
#pragma unroll
      for (int r = 0; r < 4; r++) {
        const int j = quad * 4 + r;
        float pe = accp[t][r];
        float kf = kg[jj[j] * 64 + ft];
        float vf = vg[jj[j] * 64 + ft];
        vpe[t][r] = vf + pe;
        hm[j * 64 + HCOL(ft, j)] = f2bf(qv[t] - kf + pe);
      }
    }
    f32x4 acch[4];
    mv(hm, Bf[1], ba1, ln, quad, acch);     // hh @ at_w1 + b
#pragma unroll
    for (int t = 0; t < 4; t++)
#pragma unroll
      for (int r = 0; r < 4; r++) {
        const int j = quad * 4 + r;
        hm[j * 64 + HCOL(t * 16 + ln, j)] = f2bf(fmaxf(acch[t][r], 0.f));
      }
    f32x4 lg[4];
    mv(hm, Bf[2], ba2, ln, quad, lg);       // logits
    const int pb = wid * 4 + pp;
#pragma unroll
    for (int t = 0; t < 4; t++) {
      float mx = fmaxf(fmaxf(lg[t][0], lg[t][1]), fmaxf(lg[t][2], lg[t][3]));
      mx = fmaxf(mx, __shfl_xor(mx, 16));
      mx = fmaxf(mx, __shfl_xor(mx, 32));
      float e0 = __expf((lg[t][0] - mx) * 0.125f);
      float e1 = __expf((lg[t][1] - mx) * 0.125f);
      float e2 = __expf((lg[t][2] - mx) * 0.125f);
      float e3 = __expf((lg[t][3] - mx) * 0.125f);
      float ss = (e0 + e1) + (e2 + e3);
      float dt = fmaf(e3, vpe[t][3], fmaf(e2, vpe[t][2],
                 fmaf(e1, vpe[t][1], e0 * vpe[t][0])));
      ss += __shfl_xor(ss, 16); ss += __shfl_xor(ss, 32);
      dt += __shfl_xor(dt, 16); dt += __shfl_xor(dt, 32);
      float res = dt / ss;
      if (quad == 0) resm[pb * 64 + HCOL(t * 16 + ln, pb)] = f2bf(res);
    }
  }
  __syncthreads();
  // epilogue: 16 points = 1 M-tile x 4 N-tiles; wave wid handles N-tile wid
  {
    const int nt = wid;
    float ob = wb[B_OUT + nt * 16 + ln];
    f32x4 acc = {ob, ob, ob, ob};
#pragma unroll
    for (int ks = 0; ks < 2; ks++) {
      bf16x8 a = *(const bf16x8*)(resm + ln * 64 +
                                  (((ks * 4 + quad + ln) & 7) << 3));
      bf16x8 b = *(const bf16x8*)(wt + 3 * 4096 + (nt * 16 + ln) * 64 +
                                  ks * 32 + quad * 8);
      acc = __builtin_amdgcn_mfma_f32_16x16x32_bf16(a, b, acc, 0, 0, 0);
    }
#pragma unroll
    for (int r = 0; r < 4; r++) {
      const int pt = blockIdx.x * 16 + quad * 4 + r;
      const int f = nt * 16 + ln;
      out[pt * 64 + f] = acc[r] + featf[pt * 64 + f];
    }
  }
}

// ============================ launcher ========================================
extern "C" void kernel_launch(void* const* d_in, const int* in_sizes, int n_in,
                              void* d_out, int out_size, void* d_ws, size_t ws_size,
                              hipStream_t stream)
{
  (void)in_sizes; (void)n_in; (void)out_size; (void)ws_size;
  const float* pos   = (const float*)d_in[0];
  const float* feat  = (const float*)d_in[1];
  const float* emb_w = (const float*)d_in[2];
  const float* emb_b = (const float*)d_in[3];
  const float* wq    = (const float*)d_in[4];
  const float* wk    = (const float*)d_in[5];
  const float* wv    = (const float*)d_in[6];
  const float* pe_w1 = (const float*)d_in[7];
  const float* pe_b1 = (const float*)d_in[8];
  const float* pe_w2 = (const float*)d_in[9];
  const float* pe_b2 = (const float*)d_in[10];
  const float* at_w1 = (const float*)d_in[11];
  const float* at_b1 = (const float*)d_in[12];
  const float* at_w2 = (const float*)d_in[13];
  const float* at_b2 = (const float*)d_in[14];
  const float* out_w = (const float*)d_in[15];
  const float* out_b = (const float*)d_in[16];
  float* ws = (float*)d_ws;

  k0_stage<<<259, 256, 0, stream>>>(pos, emb_w, emb_b, wq, wk, wv,
      pe_w1, pe_b1, pe_w2, pe_b2, at_w1, at_b1, at_w2, at_b2, out_w, out_b, ws);
  dim3 g1(NPTS / 256, SPL);
  k1_knn<<<g1, 256, 0, stream>>>(ws + POS4_OFF, (unsigned*)ws + PART_OFF);
  k2_merge<<<NPTS / 256, 256, 0, stream>>>((unsigned*)ws + PART_OFF,
                                           (int*)ws + IDX_OFF);
  k3_emb<<<NPTS / 32, 256, 0, stream>>>(feat, ws + WBUF_OFF, ws + XB_OFF);
  k4_qkv<<<NPTS / 32, 256, 0, stream>>>(ws + XB_OFF, ws + WBUF_OFF,
                                        ws + QB_OFF, ws + KB_OFF, ws + VB_OFF);
  k5_attn<<<NPTS / 16, 256, 0, stream>>>(ws + POS4_OFF, ws + QB_OFF, ws + KB_OFF,
      ws + VB_OFF, feat, ws + WBUF_OFF, (unsigned short*)(ws + WT_OFF),
      (int*)ws + IDX_OFF, (float*)d_out);
}